// Round 5
// baseline (818.990 us; speedup 1.0000x reference)
//
#include <hip/hip_runtime.h>
#include <cstdint>

#define NATOMS 16384
#define BGRAPH 64
#define KC     64
#define MCL    (BGRAPH*KC)   // 4096 clusters
#define HIDC   256
#define FILC   256
#define ECHC   64
#define LINT   6

typedef __bf16 bf16x8 __attribute__((ext_vector_type(8)));
typedef float  f32x4  __attribute__((ext_vector_type(4)));
typedef unsigned short u16x8 __attribute__((ext_vector_type(8)));

__device__ __forceinline__ float bf2f(unsigned short u) {
    unsigned int x = ((unsigned int)u) << 16;
    return __builtin_bit_cast(float, x);
}
__device__ __forceinline__ unsigned short f2bf(float f) {
    unsigned int u = __builtin_bit_cast(unsigned int, f);
    u += 0x7FFFu + ((u >> 16) & 1u);   // RNE
    return (unsigned short)(u >> 16);
}
// fast shifted-softplus: log(1+e^x) - ln2, via raw v_exp_f32/v_log_f32 (base-2)
__device__ __forceinline__ float ssp_fast(float x) {
    float m = fmaxf(x, 0.0f);
    float t = __builtin_amdgcn_exp2f(-fabsf(x) * 1.44269504088896341f);
    float l = __builtin_amdgcn_logf(1.0f + t);           // log2(1+t), t<=1
    return fmaf(0.69314718055994531f, l, m - 0.69314718055994531f);
}
// XOR swizzle for 256-col bf16 LDS tiles (16B-chunk granularity)
__device__ __forceinline__ int sw_off(int row, int col) {
    int s = (row + (row >> 3)) & 7;
    return row * 256 + ((((col >> 3) ^ s) << 3) | (col & 7));
}

// ---------------- coarse grain: scatter-mean atoms -> clusters ----------------
__global__ void k_coarse(const float* __restrict__ pos, const float* __restrict__ attr,
                         const int* __restrict__ subi,
                         float* __restrict__ h, unsigned short* __restrict__ h_bf,
                         float* __restrict__ cpos)
{
    const int m = blockIdx.x;
    const int t = threadIdx.x;             // 0..63
    const bool is64 = (subi[8] == 1);      // dtype sniff (i//4 pattern)
    int lo = 0, hi = NATOMS;
    while (lo < hi) { int mid = (lo + hi) >> 1;
        int v = is64 ? subi[2*mid] : subi[mid];
        if (v < m) lo = mid + 1; else hi = mid; }
    int lo2 = lo, hi2 = NATOMS;
    while (lo2 < hi2) { int mid = (lo2 + hi2) >> 1;
        int v = is64 ? subi[2*mid] : subi[mid];
        if (v < m + 1) lo2 = mid + 1; else hi2 = mid; }
    const int cnt = lo2 - lo;
    const float inv = 1.0f / (float)(cnt > 0 ? cnt : 1);

    float4 s = {0.f, 0.f, 0.f, 0.f};
    for (int a = lo; a < lo2; a++) {
        const float4 v = *reinterpret_cast<const float4*>(&attr[a*HIDC + t*4]);
        s.x += v.x; s.y += v.y; s.z += v.z; s.w += v.w;
    }
    s.x *= inv; s.y *= inv; s.z *= inv; s.w *= inv;
    *reinterpret_cast<float4*>(&h[m*HIDC + t*4]) = s;
    const int o = m*HIDC + t*4;
    h_bf[o+0] = f2bf(s.x); h_bf[o+1] = f2bf(s.y);
    h_bf[o+2] = f2bf(s.z); h_bf[o+3] = f2bf(s.w);
    if (t < 3) {
        float p = 0.f;
        for (int a = lo; a < lo2; a++) p += pos[a*3 + t];
        cpos[m*3 + t] = p * inv;
    }
}

// ---------------- pack fp32 [L][K][256] weight -> bf16 MFMA B-fragment layout --------
__global__ void k_pack(const float* __restrict__ src, unsigned short* __restrict__ dst,
                       int K, int total)
{
    int idx = blockIdx.x * 256 + threadIdx.x;
    if (idx >= total) return;
    int n = idx % 256;
    int k = (idx / 256) % K;
    int l = idx / (256 * K);
    int KT = K >> 5;
    int nt = n >> 4, kt = k >> 5, q = (k >> 3) & 3, j = k & 7;
    int lane = q*16 + (n & 15);
    dst[l*(16*KT*512) + ((nt*KT + kt)*64 + lane)*8 + j] = f2bf(src[idx]);
}

// ---------------- fused edge MLP + aggregation ----------------
// one WG (256 thr = 4 waves) per destination cluster c of molecule b.
// phi staging overlaid into G_s front (A-frags pre-read to regs) -> 33.3KB LDS
// plain launch bounds: compiler picks ~110-125 VGPR (4 waves/SIMD), NO spill.
// (R3's forced (256,4) drove the allocator to 64 VGPR + 96MB scratch traffic.)
#define PSTR 72    // phi LDS row stride (bf16), 144B = 16B-aligned
__global__ __launch_bounds__(256) void k_edge(
    const float* __restrict__ cpos, const unsigned short* __restrict__ x_bf,
    const unsigned short* __restrict__ w1p, const unsigned short* __restrict__ w2p,
    const float* __restrict__ b1, const float* __restrict__ b2,
    unsigned short* __restrict__ agg_bf)
{
    __shared__ unsigned short G_s[64 * 256];     // 32KB; phi overlaid at front
    __shared__ float d_s[64];
    __shared__ float C_s[64];

    const int wg = blockIdx.x;            // global dest cluster id
    const int b  = wg >> 6, c = wg & 63;
    const int t  = threadIdx.x;
    const int w  = t >> 6, lane = t & 63;
    const int quad = lane >> 4, l16 = lane & 15;

    if (t < 64) {
        float ax = cpos[(b*64 + t)*3 + 0] - cpos[(b*64 + c)*3 + 0];
        float ay = cpos[(b*64 + t)*3 + 1] - cpos[(b*64 + c)*3 + 1];
        float az = cpos[(b*64 + t)*3 + 2] - cpos[(b*64 + c)*3 + 2];
        float d = sqrtf(ax*ax + ay*ay + az*az);
        d_s[t] = d;
        float Cv = 0.5f * (__cosf(d * 0.31415926535897932f) + 1.0f); // pi/10
        Cv = (d <= 10.0f) ? Cv : 0.0f;
        if (t == c) Cv = 0.0f;            // no self edge
        C_s[t] = Cv;
    }
    __syncthreads();

    // ---- cooperative gaussian features phi[64 rows][64 ch] into G_s front
    const float DELTA = 10.0f / 63.0f;
    const float C2 = (-0.5f / (DELTA * DELTA)) * 1.44269504088896341f; // coeff*log2(e)
    {
        const int r = t & 63, half = t >> 6;
        float d = d_s[r];
        u16x8 ph[2];
        #pragma unroll
        for (int i = 0; i < 2; i++)
            #pragma unroll
            for (int j = 0; j < 8; j++) {
                float diff = d - (float)(half*16 + i*8 + j) * DELTA;
                ph[i][j] = f2bf(__builtin_amdgcn_exp2f(C2 * diff * diff));
            }
        *reinterpret_cast<u16x8*>(&G_s[r*PSTR + half*16    ]) = ph[0];
        *reinterpret_cast<u16x8*>(&G_s[r*PSTR + half*16 + 8]) = ph[1];
    }
    __syncthreads();

    // ---- pre-read ALL GEMM1 A-frags into regs (phi region is about to be overwritten)
    bf16x8 afr1[2][4];
    #pragma unroll
    for (int kt = 0; kt < 2; kt++)
        #pragma unroll
        for (int mt = 0; mt < 4; mt++)
            afr1[kt][mt] = *reinterpret_cast<const bf16x8*>(&G_s[(mt*16 + l16)*PSTR + kt*32 + quad*8]);
    __syncthreads();   // all phi reads done before G writes

    // ---- GEMM1: phi(64x64) @ w1(64x256)
    f32x4 acc1[4][4];
    #pragma unroll
    for (int a = 0; a < 4; a++)
        #pragma unroll
        for (int bb = 0; bb < 4; bb++) acc1[a][bb] = f32x4{0.f,0.f,0.f,0.f};

    #pragma unroll
    for (int kt = 0; kt < 2; kt++) {
        #pragma unroll
        for (int nt = 0; nt < 4; nt++) {
            const int ntg = w*4 + nt;
            bf16x8 bfr = *reinterpret_cast<const bf16x8*>(w1p + ((ntg*2 + kt)*64 + lane)*8);
            #pragma unroll
            for (int mt = 0; mt < 4; mt++)
                acc1[mt][nt] = __builtin_amdgcn_mfma_f32_16x16x32_bf16(afr1[kt][mt], bfr, acc1[mt][nt], 0, 0, 0);
        }
    }

    float b1v[4];
    #pragma unroll
    for (int nt = 0; nt < 4; nt++) b1v[nt] = b1[w*64 + nt*16 + l16];

    // ssp, fold C[row], store G~ = C*ssp(phi@w1+b1) to LDS (swizzled)
    // C re-read from LDS per mt (don't hold 16 Crow regs across GEMM2)
    #pragma unroll
    for (int mt = 0; mt < 4; mt++) {
        float Cr[4];
        #pragma unroll
        for (int i = 0; i < 4; i++) Cr[i] = C_s[mt*16 + quad*4 + i];
        #pragma unroll
        for (int nt = 0; nt < 4; nt++)
            #pragma unroll
            for (int i = 0; i < 4; i++) {
                float v = ssp_fast(acc1[mt][nt][i] + b1v[nt]) * Cr[i];
                int row = mt*16 + quad*4 + i;
                int col = w*64 + nt*16 + l16;
                G_s[sw_off(row, col)] = f2bf(v);
            }
    }
    __syncthreads();

    // ---- GEMM2: G~(64x256) @ w2(256x256)  (acc2 = C * (G@w2))
    // B-frag loaded ONCE per (kt,nt), feeds 4 row-tiles (R3 structure)
    f32x4 acc2[4][4];
    #pragma unroll
    for (int a = 0; a < 4; a++)
        #pragma unroll
        for (int bb = 0; bb < 4; bb++) acc2[a][bb] = f32x4{0.f,0.f,0.f,0.f};

    #pragma unroll
    for (int kt = 0; kt < 8; kt++) {
        bf16x8 afr[4];
        #pragma unroll
        for (int mt = 0; mt < 4; mt++) {
            int row = mt*16 + l16;
            int s = (row + (row >> 3)) & 7;
            afr[mt] = *reinterpret_cast<const bf16x8*>(&G_s[row*256 + (((kt*4 + quad) ^ s) << 3)]);
        }
        #pragma unroll
        for (int nt = 0; nt < 4; nt++) {
            const int ntg = w*4 + nt;
            bf16x8 bfr = *reinterpret_cast<const bf16x8*>(w2p + ((ntg*8 + kt)*64 + lane)*8);
            #pragma unroll
            for (int mt = 0; mt < 4; mt++)
                acc2[mt][nt] = __builtin_amdgcn_mfma_f32_16x16x32_bf16(afr[mt], bfr, acc2[mt][nt], 0, 0, 0);
        }
    }

    // ---- epilogue: agg[c,f] = sum_r x[r,f]*acc2[r,f] + b2[f]*sum_r x[r,f]*C[r]
    // x loads double-buffered one mt-group ahead (hide L2 latency under FMAs)
    float b2v[4];
    #pragma unroll
    for (int nt = 0; nt < 4; nt++) b2v[nt] = b2[w*64 + nt*16 + l16];

    const unsigned short* xb = x_bf + (size_t)b * 64 * 256;
    float colsum[4] = {0.f, 0.f, 0.f, 0.f};
    float xcsum[4]  = {0.f, 0.f, 0.f, 0.f};

    unsigned short xpre[2][16];
    #pragma unroll
    for (int e = 0; e < 16; e++) {
        int nt = e >> 2, i = e & 3;
        xpre[0][e] = xb[(quad*4 + i)*256 + w*64 + nt*16 + l16];
    }
    #pragma unroll
    for (int mt = 0; mt < 4; mt++) {
        if (mt < 3) {
            #pragma unroll
            for (int e = 0; e < 16; e++) {
                int nt = e >> 2, i = e & 3;
                xpre[(mt+1)&1][e] = xb[((mt+1)*16 + quad*4 + i)*256 + w*64 + nt*16 + l16];
            }
        }
        float Cr[4];
        #pragma unroll
        for (int i = 0; i < 4; i++) Cr[i] = C_s[mt*16 + quad*4 + i];
        #pragma unroll
        for (int nt = 0; nt < 4; nt++)
            #pragma unroll
            for (int i = 0; i < 4; i++) {
                float xv = bf2f(xpre[mt&1][nt*4 + i]);
                colsum[nt] = fmaf(xv, acc2[mt][nt][i], colsum[nt]);
                xcsum[nt] = fmaf(xv, Cr[i], xcsum[nt]);
            }
    }
    #pragma unroll
    for (int nt = 0; nt < 4; nt++) {
        colsum[nt] = fmaf(b2v[nt], xcsum[nt], colsum[nt]);
        colsum[nt] += __shfl_xor(colsum[nt], 16, 64);
        colsum[nt] += __shfl_xor(colsum[nt], 32, 64);
    }
    if (quad == 0) {
        #pragma unroll
        for (int nt = 0; nt < 4; nt++)
            agg_bf[(size_t)wg*256 + w*64 + nt*16 + l16] = f2bf(colsum[nt]);
    }
}

// ---------------- 16-row-tile GEMM helper over swizzled LDS A ----------------
__device__ __forceinline__ void gemm16(const unsigned short* A_s, const unsigned short* Bp,
                                       int w, int lane, f32x4 acc[4])
{
    const int quad = lane >> 4, l16 = lane & 15;
    const int s = (l16 + (l16 >> 3)) & 7;
    #pragma unroll
    for (int nt = 0; nt < 4; nt++) acc[nt] = f32x4{0.f,0.f,0.f,0.f};
    #pragma unroll
    for (int kt = 0; kt < 8; kt++) {
        bf16x8 afr = *reinterpret_cast<const bf16x8*>(&A_s[l16*256 + (((kt*4 + quad) ^ s) << 3)]);
        #pragma unroll
        for (int nt = 0; nt < 4; nt++) {
            bf16x8 bfr = *reinterpret_cast<const bf16x8*>(Bp + (((w*4 + nt)*8 + kt)*64 + lane)*8);
            acc[nt] = __builtin_amdgcn_mfma_f32_16x16x32_bf16(afr, bfr, acc[nt], 0, 0, 0);
        }
    }
}

// ---------------- initial x0 = h @ lin1 (4096x256)@(256x256) ----------------
__global__ __launch_bounds__(256) void k_gemm0(
    const unsigned short* __restrict__ A_bf, const unsigned short* __restrict__ Bp,
    unsigned short* __restrict__ out_bf)
{
    __shared__ unsigned short A_s[16 * 256];
    const int mb = blockIdx.x;     // 256 blocks of 16 rows
    const int t = threadIdx.x;
    const int w = t >> 6, lane = t & 63, quad = lane >> 4, l16 = lane & 15;

    {   // stage 16x256 tile, swizzled
        int r = t >> 4, seg = t & 15;
        int s = (r + (r >> 3)) & 7;
        const u16x8* src = reinterpret_cast<const u16x8*>(A_bf + (size_t)(mb*16 + r)*256 + seg*16);
        int c = seg*2;
        *reinterpret_cast<u16x8*>(&A_s[r*256 + (((c  ) ^ s) << 3)]) = src[0];
        *reinterpret_cast<u16x8*>(&A_s[r*256 + (((c+1) ^ s) << 3)]) = src[1];
    }
    __syncthreads();

    f32x4 acc[4];
    gemm16(A_s, Bp, w, lane, acc);

    #pragma unroll
    for (int nt = 0; nt < 4; nt++)
        #pragma unroll
        for (int i = 0; i < 4; i++) {
            int rg = mb*16 + quad*4 + i;
            int col = w*64 + nt*16 + l16;
            out_bf[(size_t)rg*256 + col] = f2bf(acc[nt][i]);
        }
}

// ---------------- fused tail: y=ssp(agg@lin2+b2); h+=y@lin_w+b; x=h@lin1_next ----
template<int DO_X>
__global__ __launch_bounds__(256) void k_tail(
    const unsigned short* __restrict__ agg_bf,
    const unsigned short* __restrict__ lin2p, const float* __restrict__ lin2_b,
    const unsigned short* __restrict__ linp,  const float* __restrict__ lin_b,
    const unsigned short* __restrict__ lin1p,
    float* __restrict__ h, unsigned short* __restrict__ x_bf)
{
    __shared__ unsigned short A_s[16 * 256];
    const int mb = blockIdx.x;     // 256 blocks of 16 rows
    const int t = threadIdx.x;
    const int w = t >> 6, lane = t & 63, quad = lane >> 4, l16 = lane & 15;

    {   // stage agg 16x256 tile, swizzled
        int r = t >> 4, seg = t & 15;
        int s = (r + (r >> 3)) & 7;
        const u16x8* src = reinterpret_cast<const u16x8*>(agg_bf + (size_t)(mb*16 + r)*256 + seg*16);
        int c = seg*2;
        *reinterpret_cast<u16x8*>(&A_s[r*256 + (((c  ) ^ s) << 3)]) = src[0];
        *reinterpret_cast<u16x8*>(&A_s[r*256 + (((c+1) ^ s) << 3)]) = src[1];
    }
    __syncthreads();

    f32x4 acc[4];
    // stage 1: y = ssp(agg @ lin2 + lin2_b)
    gemm16(A_s, lin2p, w, lane, acc);
    float bv[4];
    #pragma unroll
    for (int nt = 0; nt < 4; nt++) bv[nt] = lin2_b[w*64 + nt*16 + l16];
    __syncthreads();
    #pragma unroll
    for (int nt = 0; nt < 4; nt++)
        #pragma unroll
        for (int i = 0; i < 4; i++) {
            int row = quad*4 + i, col = w*64 + nt*16 + l16;
            A_s[sw_off(row, col)] = f2bf(ssp_fast(acc[nt][i] + bv[nt]));
        }
    __syncthreads();

    // stage 2: h' = h + y @ lin_w + lin_b   (fp32 residual)
    gemm16(A_s, linp, w, lane, acc);
    #pragma unroll
    for (int nt = 0; nt < 4; nt++) bv[nt] = lin_b[w*64 + nt*16 + l16];
    float hv[4][4];
    #pragma unroll
    for (int nt = 0; nt < 4; nt++)
        #pragma unroll
        for (int i = 0; i < 4; i++) {
            int rg = mb*16 + quad*4 + i;
            int col = w*64 + nt*16 + l16;
            float v = acc[nt][i] + bv[nt] + h[(size_t)rg*256 + col];
            h[(size_t)rg*256 + col] = v;
            hv[nt][i] = v;
        }
    if (DO_X) {
        __syncthreads();
        #pragma unroll
        for (int nt = 0; nt < 4; nt++)
            #pragma unroll
            for (int i = 0; i < 4; i++) {
                int row = quad*4 + i, col = w*64 + nt*16 + l16;
                A_s[sw_off(row, col)] = f2bf(hv[nt][i]);
            }
        __syncthreads();
        // stage 3: x_next = h' @ lin1_next
        gemm16(A_s, lin1p, w, lane, acc);
        #pragma unroll
        for (int nt = 0; nt < 4; nt++)
            #pragma unroll
            for (int i = 0; i < 4; i++) {
                int rg = mb*16 + quad*4 + i;
                int col = w*64 + nt*16 + l16;
                x_bf[(size_t)rg*256 + col] = f2bf(acc[nt][i]);
            }
    }
}

// ---------------- host ----------------
extern "C" void kernel_launch(void* const* d_in, const int* in_sizes, int n_in,
                              void* d_out, int out_size, void* d_ws, size_t ws_size,
                              hipStream_t stream)
{
    const float* pos    = (const float*)d_in[0];
    const float* nattr  = (const float*)d_in[1];
    const int*   subi   = (const int*)d_in[2];
    const float* mlp_w1 = (const float*)d_in[6];
    const float* mlp_b1 = (const float*)d_in[7];
    const float* mlp_w2 = (const float*)d_in[8];
    const float* mlp_b2 = (const float*)d_in[9];
    const float* lin1_w = (const float*)d_in[10];
    const float* lin2_w = (const float*)d_in[11];
    const float* lin2_b = (const float*)d_in[12];
    const float* lin_w  = (const float*)d_in[13];
    const float* lin_b  = (const float*)d_in[14];
    float* h = (float*)d_out;        // fp32 h lives in d_out across all layers

    char* p = (char*)d_ws;
    auto alloc = [&](size_t bytes) { char* r = p; p += (bytes + 255) & ~(size_t)255; return r; };
    unsigned short* h_bf   = (unsigned short*)alloc((size_t)MCL*256*2);
    unsigned short* x_bf   = (unsigned short*)alloc((size_t)MCL*256*2);
    unsigned short* agg_bf = (unsigned short*)alloc((size_t)MCL*256*2);
    float*          cpos   = (float*)alloc((size_t)MCL*3*4);
    unsigned short* w1p    = (unsigned short*)alloc((size_t)LINT*16384*2);
    unsigned short* w2p    = (unsigned short*)alloc((size_t)LINT*65536*2);
    unsigned short* lin1p  = (unsigned short*)alloc((size_t)LINT*65536*2);
    unsigned short* lin2p  = (unsigned short*)alloc((size_t)LINT*65536*2);
    unsigned short* linp   = (unsigned short*)alloc((size_t)LINT*65536*2);

    k_coarse<<<MCL, 64, 0, stream>>>(pos, nattr, subi, h, h_bf, cpos);
    k_pack<<<(LINT*64*256 + 255)/256, 256, 0, stream>>>(mlp_w1, w1p, 64, LINT*64*256);
    k_pack<<<(LINT*65536 + 255)/256, 256, 0, stream>>>(mlp_w2, w2p, 256, LINT*65536);
    k_pack<<<(LINT*65536 + 255)/256, 256, 0, stream>>>(lin1_w, lin1p, 256, LINT*65536);
    k_pack<<<(LINT*65536 + 255)/256, 256, 0, stream>>>(lin2_w, lin2p, 256, LINT*65536);
    k_pack<<<(LINT*65536 + 255)/256, 256, 0, stream>>>(lin_w,  linp,  256, LINT*65536);

    // x0 = h @ lin1[0]
    k_gemm0<<<256, 256, 0, stream>>>(h_bf, lin1p, x_bf);

    for (int l = 0; l < LINT; l++) {
        k_edge<<<MCL, 256, 0, stream>>>(cpos, x_bf, w1p + (size_t)l*16384, w2p + (size_t)l*65536,
                                        mlp_b1 + l*256, mlp_b2 + l*256, agg_bf);
        if (l < LINT-1) {
            k_tail<1><<<256, 256, 0, stream>>>(agg_bf, lin2p + (size_t)l*65536, lin2_b + l*256,
                                               linp + (size_t)l*65536, lin_b + l*256,
                                               lin1p + (size_t)(l+1)*65536, h, x_bf);
        } else {
            k_tail<0><<<256, 256, 0, stream>>>(agg_bf, lin2p + (size_t)l*65536, lin2_b + l*256,
                                               linp + (size_t)l*65536, lin_b + l*256,
                                               lin1p, h, x_bf);
        }
    }
}

// Round 6
// 593.898 us; speedup vs baseline: 1.3790x; 1.3790x over previous
//
#include <hip/hip_runtime.h>
#include <cstdint>

#define NATOMS 16384
#define BGRAPH 64
#define KC     64
#define MCL    (BGRAPH*KC)   // 4096 clusters
#define HIDC   256
#define FILC   256
#define ECHC   64
#define LINT   6

typedef __bf16 bf16x8 __attribute__((ext_vector_type(8)));
typedef float  f32x4  __attribute__((ext_vector_type(4)));
typedef unsigned short u16x8 __attribute__((ext_vector_type(8)));

__device__ __forceinline__ float bf2f(unsigned short u) {
    unsigned int x = ((unsigned int)u) << 16;
    return __builtin_bit_cast(float, x);
}
__device__ __forceinline__ unsigned short f2bf(float f) {
    unsigned int u = __builtin_bit_cast(unsigned int, f);
    u += 0x7FFFu + ((u >> 16) & 1u);   // RNE
    return (unsigned short)(u >> 16);
}
// fast shifted-softplus: log(1+e^x) - ln2, via raw v_exp_f32/v_log_f32 (base-2)
__device__ __forceinline__ float ssp_fast(float x) {
    float m = fmaxf(x, 0.0f);
    float t = __builtin_amdgcn_exp2f(-fabsf(x) * 1.44269504088896341f);
    float l = __builtin_amdgcn_logf(1.0f + t);           // log2(1+t), t<=1
    return fmaf(0.69314718055994531f, l, m - 0.69314718055994531f);
}
// XOR swizzle for 256-col bf16 LDS tiles (16B-chunk granularity)
__device__ __forceinline__ int sw_off(int row, int col) {
    int s = (row + (row >> 3)) & 7;
    return row * 256 + ((((col >> 3) ^ s) << 3) | (col & 7));
}
// row-dependent chunk swizzle for the 64-col phi tile: rows r and r+8 must map
// to different banks (row stride 64 u16 = 32 words wraps the bank space).
__device__ __forceinline__ int phi_sw(int row) {
    return ((row & 7) ^ ((row >> 3) & 7)) & 7;
}

// ---------------- coarse grain: scatter-mean atoms -> clusters ----------------
__global__ void k_coarse(const float* __restrict__ pos, const float* __restrict__ attr,
                         const int* __restrict__ subi,
                         float* __restrict__ h, unsigned short* __restrict__ h_bf,
                         float* __restrict__ cpos)
{
    const int m = blockIdx.x;
    const int t = threadIdx.x;             // 0..63
    const bool is64 = (subi[8] == 1);      // dtype sniff (i//4 pattern)
    int lo = 0, hi = NATOMS;
    while (lo < hi) { int mid = (lo + hi) >> 1;
        int v = is64 ? subi[2*mid] : subi[mid];
        if (v < m) lo = mid + 1; else hi = mid; }
    int lo2 = lo, hi2 = NATOMS;
    while (lo2 < hi2) { int mid = (lo2 + hi2) >> 1;
        int v = is64 ? subi[2*mid] : subi[mid];
        if (v < m + 1) lo2 = mid + 1; else hi2 = mid; }
    const int cnt = lo2 - lo;
    const float inv = 1.0f / (float)(cnt > 0 ? cnt : 1);

    float4 s = {0.f, 0.f, 0.f, 0.f};
    for (int a = lo; a < lo2; a++) {
        const float4 v = *reinterpret_cast<const float4*>(&attr[a*HIDC + t*4]);
        s.x += v.x; s.y += v.y; s.z += v.z; s.w += v.w;
    }
    s.x *= inv; s.y *= inv; s.z *= inv; s.w *= inv;
    *reinterpret_cast<float4*>(&h[m*HIDC + t*4]) = s;
    const int o = m*HIDC + t*4;
    h_bf[o+0] = f2bf(s.x); h_bf[o+1] = f2bf(s.y);
    h_bf[o+2] = f2bf(s.z); h_bf[o+3] = f2bf(s.w);
    if (t < 3) {
        float p = 0.f;
        for (int a = lo; a < lo2; a++) p += pos[a*3 + t];
        cpos[m*3 + t] = p * inv;
    }
}

// ---------------- pack fp32 [L][K][256] weight -> bf16 MFMA B-fragment layout --------
__global__ void k_pack(const float* __restrict__ src, unsigned short* __restrict__ dst,
                       int K, int total)
{
    int idx = blockIdx.x * 256 + threadIdx.x;
    if (idx >= total) return;
    int n = idx % 256;
    int k = (idx / 256) % K;
    int l = idx / (256 * K);
    int KT = K >> 5;
    int nt = n >> 4, kt = k >> 5, q = (k >> 3) & 3, j = k & 7;
    int lane = q*16 + (n & 15);
    dst[l*(16*KT*512) + ((nt*KT + kt)*64 + lane)*8 + j] = f2bf(src[idx]);
}

// ---------------- fused edge MLP + aggregation ----------------
// one WG (512 thr = 8 waves) per destination cluster c of molecule b.
// Each wave owns 32 output columns (2 nt-tiles): acc = 32 f32/thread -> fits
// forced 6 waves/EU (24 waves/CU, 75% occ) without the R3 spill.
// R2-R5 evidence: occupancy/latency dominates this kernel; forced density won
// every time it was tried (R3: 84us w/ 96MB spill vs R4/R5 unforced: 107-126us).
__global__ __launch_bounds__(512, 6) void k_edge(
    const float* __restrict__ cpos, const unsigned short* __restrict__ x_bf,
    const unsigned short* __restrict__ w1p, const unsigned short* __restrict__ w2p,
    const float* __restrict__ b1, const float* __restrict__ b2,
    unsigned short* __restrict__ agg_bf)
{
    __shared__ unsigned short G_s[64 * 256];     // 32KB; phi overlaid at front (8KB)
    __shared__ float d_s[64];
    __shared__ float C_s[64];

    const int wg = blockIdx.x;            // global dest cluster id
    const int b  = wg >> 6, c = wg & 63;
    const int t  = threadIdx.x;
    const int w  = t >> 6, lane = t & 63; // w = wave 0..7
    const int quad = lane >> 4, l16 = lane & 15;

    if (t < 64) {
        float ax = cpos[(b*64 + t)*3 + 0] - cpos[(b*64 + c)*3 + 0];
        float ay = cpos[(b*64 + t)*3 + 1] - cpos[(b*64 + c)*3 + 1];
        float az = cpos[(b*64 + t)*3 + 2] - cpos[(b*64 + c)*3 + 2];
        float d = sqrtf(ax*ax + ay*ay + az*az);
        d_s[t] = d;
        float Cv = 0.5f * (__cosf(d * 0.31415926535897932f) + 1.0f); // pi/10
        Cv = (d <= 10.0f) ? Cv : 0.0f;
        if (t == c) Cv = 0.0f;            // no self edge
        C_s[t] = Cv;
    }
    __syncthreads();

    // ---- cooperative gaussian features phi[64 rows][64 ch] into G_s front
    // 512 threads: thread (r=lane, oct=w) computes 8 channels, one b128 store.
    const float DELTA = 10.0f / 63.0f;
    const float C2 = (-0.5f / (DELTA * DELTA)) * 1.44269504088896341f; // coeff*log2(e)
    {
        float d = d_s[lane];
        u16x8 ph;
        #pragma unroll
        for (int j = 0; j < 8; j++) {
            float diff = d - (float)(w*8 + j) * DELTA;
            ph[j] = f2bf(__builtin_amdgcn_exp2f(C2 * diff * diff));
        }
        *reinterpret_cast<u16x8*>(&G_s[lane*64 + ((w ^ phi_sw(lane)) << 3)]) = ph;
    }
    __syncthreads();

    // ---- pre-read ALL GEMM1 A-frags (phi region is overwritten by G stores)
    bf16x8 afr1[2][4];
    #pragma unroll
    for (int kt = 0; kt < 2; kt++)
        #pragma unroll
        for (int mt = 0; mt < 4; mt++) {
            int row = mt*16 + l16;
            afr1[kt][mt] = *reinterpret_cast<const bf16x8*>(
                &G_s[row*64 + (((kt*4 + quad) ^ phi_sw(row)) << 3)]);
        }
    __syncthreads();   // all phi reads done before G writes

    // ---- GEMM1: phi(64x64) @ w1(64x256), this wave's 2 nt-tiles
    f32x4 acc1[4][2];
    #pragma unroll
    for (int a = 0; a < 4; a++)
        #pragma unroll
        for (int bb = 0; bb < 2; bb++) acc1[a][bb] = f32x4{0.f,0.f,0.f,0.f};

    #pragma unroll
    for (int kt = 0; kt < 2; kt++) {
        #pragma unroll
        for (int nt = 0; nt < 2; nt++) {
            const int ntg = w*2 + nt;
            bf16x8 bfr = *reinterpret_cast<const bf16x8*>(w1p + ((ntg*2 + kt)*64 + lane)*8);
            #pragma unroll
            for (int mt = 0; mt < 4; mt++)
                acc1[mt][nt] = __builtin_amdgcn_mfma_f32_16x16x32_bf16(afr1[kt][mt], bfr, acc1[mt][nt], 0, 0, 0);
        }
    }

    float b1v[2];
    #pragma unroll
    for (int nt = 0; nt < 2; nt++) b1v[nt] = b1[(w*2 + nt)*16 + l16];

    // ssp, fold C[row], store G~ = C*ssp(phi@w1+b1) to LDS (swizzled)
    #pragma unroll
    for (int mt = 0; mt < 4; mt++) {
        float Cr[4];
        #pragma unroll
        for (int i = 0; i < 4; i++) Cr[i] = C_s[mt*16 + quad*4 + i];
        #pragma unroll
        for (int nt = 0; nt < 2; nt++)
            #pragma unroll
            for (int i = 0; i < 4; i++) {
                float v = ssp_fast(acc1[mt][nt][i] + b1v[nt]) * Cr[i];
                int row = mt*16 + quad*4 + i;
                int col = (w*2 + nt)*16 + l16;
                G_s[sw_off(row, col)] = f2bf(v);
            }
    }
    __syncthreads();

    // ---- GEMM2: G~(64x256) @ w2(256x256)  (acc2 = C * (G@w2))
    f32x4 acc2[4][2];
    #pragma unroll
    for (int a = 0; a < 4; a++)
        #pragma unroll
        for (int bb = 0; bb < 2; bb++) acc2[a][bb] = f32x4{0.f,0.f,0.f,0.f};

    #pragma unroll
    for (int kt = 0; kt < 8; kt++) {
        bf16x8 afr[4];
        #pragma unroll
        for (int mt = 0; mt < 4; mt++) {
            int row = mt*16 + l16;
            int s = (row + (row >> 3)) & 7;
            afr[mt] = *reinterpret_cast<const bf16x8*>(&G_s[row*256 + (((kt*4 + quad) ^ s) << 3)]);
        }
        #pragma unroll
        for (int nt = 0; nt < 2; nt++) {
            const int ntg = w*2 + nt;
            bf16x8 bfr = *reinterpret_cast<const bf16x8*>(w2p + ((ntg*8 + kt)*64 + lane)*8);
            #pragma unroll
            for (int mt = 0; mt < 4; mt++)
                acc2[mt][nt] = __builtin_amdgcn_mfma_f32_16x16x32_bf16(afr[mt], bfr, acc2[mt][nt], 0, 0, 0);
        }
    }

    // ---- epilogue: agg[c,f] = sum_r x[r,f]*acc2[r,f] + b2[f]*sum_r x[r,f]*C[r]
    float b2v[2];
    #pragma unroll
    for (int nt = 0; nt < 2; nt++) b2v[nt] = b2[(w*2 + nt)*16 + l16];

    const unsigned short* xb = x_bf + (size_t)b * 64 * 256;
    float colsum[2] = {0.f, 0.f};
    float xcsum[2]  = {0.f, 0.f};

    unsigned short xpre[2][8];
    #pragma unroll
    for (int e = 0; e < 8; e++) {
        int nt = e >> 2, i = e & 3;
        xpre[0][e] = xb[(quad*4 + i)*256 + (w*2 + nt)*16 + l16];
    }
    #pragma unroll
    for (int mt = 0; mt < 4; mt++) {
        if (mt < 3) {
            #pragma unroll
            for (int e = 0; e < 8; e++) {
                int nt = e >> 2, i = e & 3;
                xpre[(mt+1)&1][e] = xb[((mt+1)*16 + quad*4 + i)*256 + (w*2 + nt)*16 + l16];
            }
        }
        float Cr[4];
        #pragma unroll
        for (int i = 0; i < 4; i++) Cr[i] = C_s[mt*16 + quad*4 + i];
        #pragma unroll
        for (int nt = 0; nt < 2; nt++)
            #pragma unroll
            for (int i = 0; i < 4; i++) {
                float xv = bf2f(xpre[mt&1][nt*4 + i]);
                colsum[nt] = fmaf(xv, acc2[mt][nt][i], colsum[nt]);
                xcsum[nt] = fmaf(xv, Cr[i], xcsum[nt]);
            }
    }
    #pragma unroll
    for (int nt = 0; nt < 2; nt++) {
        colsum[nt] = fmaf(b2v[nt], xcsum[nt], colsum[nt]);
        colsum[nt] += __shfl_xor(colsum[nt], 16, 64);
        colsum[nt] += __shfl_xor(colsum[nt], 32, 64);
    }
    if (quad == 0) {
        #pragma unroll
        for (int nt = 0; nt < 2; nt++)
            agg_bf[(size_t)wg*256 + (w*2 + nt)*16 + l16] = f2bf(colsum[nt]);
    }
}

// ---------------- 16-row-tile GEMM helper over swizzled LDS A ----------------
__device__ __forceinline__ void gemm16(const unsigned short* A_s, const unsigned short* Bp,
                                       int w, int lane, f32x4 acc[4])
{
    const int quad = lane >> 4, l16 = lane & 15;
    const int s = (l16 + (l16 >> 3)) & 7;
    #pragma unroll
    for (int nt = 0; nt < 4; nt++) acc[nt] = f32x4{0.f,0.f,0.f,0.f};
    #pragma unroll
    for (int kt = 0; kt < 8; kt++) {
        bf16x8 afr = *reinterpret_cast<const bf16x8*>(&A_s[l16*256 + (((kt*4 + quad) ^ s) << 3)]);
        #pragma unroll
        for (int nt = 0; nt < 4; nt++) {
            bf16x8 bfr = *reinterpret_cast<const bf16x8*>(Bp + (((w*4 + nt)*8 + kt)*64 + lane)*8);
            acc[nt] = __builtin_amdgcn_mfma_f32_16x16x32_bf16(afr, bfr, acc[nt], 0, 0, 0);
        }
    }
}

// ---------------- initial x0 = h @ lin1 (4096x256)@(256x256) ----------------
__global__ __launch_bounds__(256) void k_gemm0(
    const unsigned short* __restrict__ A_bf, const unsigned short* __restrict__ Bp,
    unsigned short* __restrict__ out_bf)
{
    __shared__ unsigned short A_s[16 * 256];
    const int mb = blockIdx.x;     // 256 blocks of 16 rows
    const int t = threadIdx.x;
    const int w = t >> 6, lane = t & 63, quad = lane >> 4, l16 = lane & 15;

    {   // stage 16x256 tile, swizzled
        int r = t >> 4, seg = t & 15;
        int s = (r + (r >> 3)) & 7;
        const u16x8* src = reinterpret_cast<const u16x8*>(A_bf + (size_t)(mb*16 + r)*256 + seg*16);
        int c = seg*2;
        *reinterpret_cast<u16x8*>(&A_s[r*256 + (((c  ) ^ s) << 3)]) = src[0];
        *reinterpret_cast<u16x8*>(&A_s[r*256 + (((c+1) ^ s) << 3)]) = src[1];
    }
    __syncthreads();

    f32x4 acc[4];
    gemm16(A_s, Bp, w, lane, acc);

    #pragma unroll
    for (int nt = 0; nt < 4; nt++)
        #pragma unroll
        for (int i = 0; i < 4; i++) {
            int rg = mb*16 + quad*4 + i;
            int col = w*64 + nt*16 + l16;
            out_bf[(size_t)rg*256 + col] = f2bf(acc[nt][i]);
        }
}

// ---------------- fused tail: y=ssp(agg@lin2+b2); h+=y@lin_w+b; x=h@lin1_next ----
template<int DO_X>
__global__ __launch_bounds__(256) void k_tail(
    const unsigned short* __restrict__ agg_bf,
    const unsigned short* __restrict__ lin2p, const float* __restrict__ lin2_b,
    const unsigned short* __restrict__ linp,  const float* __restrict__ lin_b,
    const unsigned short* __restrict__ lin1p,
    float* __restrict__ h, unsigned short* __restrict__ x_bf)
{
    __shared__ unsigned short A_s[16 * 256];
    const int mb = blockIdx.x;     // 256 blocks of 16 rows
    const int t = threadIdx.x;
    const int w = t >> 6, lane = t & 63, quad = lane >> 4, l16 = lane & 15;

    {   // stage agg 16x256 tile, swizzled
        int r = t >> 4, seg = t & 15;
        int s = (r + (r >> 3)) & 7;
        const u16x8* src = reinterpret_cast<const u16x8*>(agg_bf + (size_t)(mb*16 + r)*256 + seg*16);
        int c = seg*2;
        *reinterpret_cast<u16x8*>(&A_s[r*256 + (((c  ) ^ s) << 3)]) = src[0];
        *reinterpret_cast<u16x8*>(&A_s[r*256 + (((c+1) ^ s) << 3)]) = src[1];
    }
    __syncthreads();

    f32x4 acc[4];
    // stage 1: y = ssp(agg @ lin2 + lin2_b)
    gemm16(A_s, lin2p, w, lane, acc);
    float bv[4];
    #pragma unroll
    for (int nt = 0; nt < 4; nt++) bv[nt] = lin2_b[w*64 + nt*16 + l16];
    __syncthreads();
    #pragma unroll
    for (int nt = 0; nt < 4; nt++)
        #pragma unroll
        for (int i = 0; i < 4; i++) {
            int row = quad*4 + i, col = w*64 + nt*16 + l16;
            A_s[sw_off(row, col)] = f2bf(ssp_fast(acc[nt][i] + bv[nt]));
        }
    __syncthreads();

    // stage 2: h' = h + y @ lin_w + lin_b   (fp32 residual)
    gemm16(A_s, linp, w, lane, acc);
    #pragma unroll
    for (int nt = 0; nt < 4; nt++) bv[nt] = lin_b[w*64 + nt*16 + l16];
    float hv[4][4];
    #pragma unroll
    for (int nt = 0; nt < 4; nt++)
        #pragma unroll
        for (int i = 0; i < 4; i++) {
            int rg = mb*16 + quad*4 + i;
            int col = w*64 + nt*16 + l16;
            float v = acc[nt][i] + bv[nt] + h[(size_t)rg*256 + col];
            h[(size_t)rg*256 + col] = v;
            hv[nt][i] = v;
        }
    if (DO_X) {
        __syncthreads();
        #pragma unroll
        for (int nt = 0; nt < 4; nt++)
            #pragma unroll
            for (int i = 0; i < 4; i++) {
                int row = quad*4 + i, col = w*64 + nt*16 + l16;
                A_s[sw_off(row, col)] = f2bf(hv[nt][i]);
            }
        __syncthreads();
        // stage 3: x_next = h' @ lin1_next
        gemm16(A_s, lin1p, w, lane, acc);
        #pragma unroll
        for (int nt = 0; nt < 4; nt++)
            #pragma unroll
            for (int i = 0; i < 4; i++) {
                int rg = mb*16 + quad*4 + i;
                int col = w*64 + nt*16 + l16;
                x_bf[(size_t)rg*256 + col] = f2bf(acc[nt][i]);
            }
    }
}

// ---------------- host ----------------
extern "C" void kernel_launch(void* const* d_in, const int* in_sizes, int n_in,
                              void* d_out, int out_size, void* d_ws, size_t ws_size,
                              hipStream_t stream)
{
    const float* pos    = (const float*)d_in[0];
    const float* nattr  = (const float*)d_in[1];
    const int*   subi   = (const int*)d_in[2];
    const float* mlp_w1 = (const float*)d_in[6];
    const float* mlp_b1 = (const float*)d_in[7];
    const float* mlp_w2 = (const float*)d_in[8];
    const float* mlp_b2 = (const float*)d_in[9];
    const float* lin1_w = (const float*)d_in[10];
    const float* lin2_w = (const float*)d_in[11];
    const float* lin2_b = (const float*)d_in[12];
    const float* lin_w  = (const float*)d_in[13];
    const float* lin_b  = (const float*)d_in[14];
    float* h = (float*)d_out;        // fp32 h lives in d_out across all layers

    char* p = (char*)d_ws;
    auto alloc = [&](size_t bytes) { char* r = p; p += (bytes + 255) & ~(size_t)255; return r; };
    unsigned short* h_bf   = (unsigned short*)alloc((size_t)MCL*256*2);
    unsigned short* x_bf   = (unsigned short*)alloc((size_t)MCL*256*2);
    unsigned short* agg_bf = (unsigned short*)alloc((size_t)MCL*256*2);
    float*          cpos   = (float*)alloc((size_t)MCL*3*4);
    unsigned short* w1p    = (unsigned short*)alloc((size_t)LINT*16384*2);
    unsigned short* w2p    = (unsigned short*)alloc((size_t)LINT*65536*2);
    unsigned short* lin1p  = (unsigned short*)alloc((size_t)LINT*65536*2);
    unsigned short* lin2p  = (unsigned short*)alloc((size_t)LINT*65536*2);
    unsigned short* linp   = (unsigned short*)alloc((size_t)LINT*65536*2);

    k_coarse<<<MCL, 64, 0, stream>>>(pos, nattr, subi, h, h_bf, cpos);
    k_pack<<<(LINT*64*256 + 255)/256, 256, 0, stream>>>(mlp_w1, w1p, 64, LINT*64*256);
    k_pack<<<(LINT*65536 + 255)/256, 256, 0, stream>>>(mlp_w2, w2p, 256, LINT*65536);
    k_pack<<<(LINT*65536 + 255)/256, 256, 0, stream>>>(lin1_w, lin1p, 256, LINT*65536);
    k_pack<<<(LINT*65536 + 255)/256, 256, 0, stream>>>(lin2_w, lin2p, 256, LINT*65536);
    k_pack<<<(LINT*65536 + 255)/256, 256, 0, stream>>>(lin_w,  linp,  256, LINT*65536);

    // x0 = h @ lin1[0]
    k_gemm0<<<256, 256, 0, stream>>>(h_bf, lin1p, x_bf);

    for (int l = 0; l < LINT; l++) {
        k_edge<<<MCL, 512, 0, stream>>>(cpos, x_bf, w1p + (size_t)l*16384, w2p + (size_t)l*65536,
                                        mlp_b1 + l*256, mlp_b2 + l*256, agg_bf);
        if (l < LINT-1) {
            k_tail<1><<<256, 256, 0, stream>>>(agg_bf, lin2p + (size_t)l*65536, lin2_b + l*256,
                                               linp + (size_t)l*65536, lin_b + l*256,
                                               lin1p + (size_t)(l+1)*65536, h, x_bf);
        } else {
            k_tail<0><<<256, 256, 0, stream>>>(agg_bf, lin2p + (size_t)l*65536, lin2_b + l*256,
                                               linp + (size_t)l*65536, lin_b + l*256,
                                               lin1p, h, x_bf);
        }
    }
}

// Round 7
// 558.153 us; speedup vs baseline: 1.4673x; 1.0640x over previous
//
#include <hip/hip_runtime.h>
#include <cstdint>

#define NATOMS 16384
#define BGRAPH 64
#define KC     64
#define MCL    (BGRAPH*KC)   // 4096 clusters
#define HIDC   256
#define FILC   256
#define ECHC   64
#define LINT   6

typedef __bf16 bf16x8 __attribute__((ext_vector_type(8)));
typedef __bf16 bf16x2 __attribute__((ext_vector_type(2)));
typedef float  f32x4  __attribute__((ext_vector_type(4)));
typedef unsigned short u16x8 __attribute__((ext_vector_type(8)));

__device__ __forceinline__ float bf2f(unsigned short u) {
    unsigned int x = ((unsigned int)u) << 16;
    return __builtin_bit_cast(float, x);
}
__device__ __forceinline__ unsigned short f2bf(float f) {
    unsigned int u = __builtin_bit_cast(unsigned int, f);
    u += 0x7FFFu + ((u >> 16) & 1u);   // RNE
    return (unsigned short)(u >> 16);
}
// packed f32x2 -> bf16x2 (low = first arg). gfx950 has v_cvt_pk_bf16_f32.
__device__ __forceinline__ unsigned int pk2(float a, float b) {
#if __has_builtin(__builtin_amdgcn_cvt_pk_bf16_f32)
    bf16x2 v = __builtin_amdgcn_cvt_pk_bf16_f32(a, b);
    return __builtin_bit_cast(unsigned int, v);
#else
    return (unsigned int)f2bf(a) | ((unsigned int)f2bf(b) << 16);
#endif
}
// fast shifted-softplus: log(1+e^x) - ln2, via raw v_exp_f32/v_log_f32 (base-2)
__device__ __forceinline__ float ssp_fast(float x) {
    float m = fmaxf(x, 0.0f);
    float t = __builtin_amdgcn_exp2f(-fabsf(x) * 1.44269504088896341f);
    float l = __builtin_amdgcn_logf(1.0f + t);           // log2(1+t), t<=1
    return fmaf(0.69314718055994531f, l, m - 0.69314718055994531f);
}
// XOR swizzle for 256-col bf16 LDS tiles (16B-chunk granularity)
__device__ __forceinline__ int sw_off(int row, int col) {
    int s = (row + (row >> 3)) & 7;
    return row * 256 + ((((col >> 3) ^ s) << 3) | (col & 7));
}
// row-dependent chunk swizzle for the 64-col phi tile
__device__ __forceinline__ int phi_sw(int row) {
    return ((row & 7) ^ ((row >> 3) & 7)) & 7;
}

// ---------------- coarse grain: scatter-mean atoms -> clusters ----------------
__global__ void k_coarse(const float* __restrict__ pos, const float* __restrict__ attr,
                         const int* __restrict__ subi,
                         float* __restrict__ h, unsigned short* __restrict__ h_bf,
                         float* __restrict__ cpos)
{
    const int m = blockIdx.x;
    const int t = threadIdx.x;             // 0..63
    const bool is64 = (subi[8] == 1);      // dtype sniff (i//4 pattern)
    int lo = 0, hi = NATOMS;
    while (lo < hi) { int mid = (lo + hi) >> 1;
        int v = is64 ? subi[2*mid] : subi[mid];
        if (v < m) lo = mid + 1; else hi = mid; }
    int lo2 = lo, hi2 = NATOMS;
    while (lo2 < hi2) { int mid = (lo2 + hi2) >> 1;
        int v = is64 ? subi[2*mid] : subi[mid];
        if (v < m + 1) lo2 = mid + 1; else hi2 = mid; }
    const int cnt = lo2 - lo;
    const float inv = 1.0f / (float)(cnt > 0 ? cnt : 1);

    float4 s = {0.f, 0.f, 0.f, 0.f};
    for (int a = lo; a < lo2; a++) {
        const float4 v = *reinterpret_cast<const float4*>(&attr[a*HIDC + t*4]);
        s.x += v.x; s.y += v.y; s.z += v.z; s.w += v.w;
    }
    s.x *= inv; s.y *= inv; s.z *= inv; s.w *= inv;
    *reinterpret_cast<float4*>(&h[m*HIDC + t*4]) = s;
    const int o = m*HIDC + t*4;
    h_bf[o+0] = f2bf(s.x); h_bf[o+1] = f2bf(s.y);
    h_bf[o+2] = f2bf(s.z); h_bf[o+3] = f2bf(s.w);
    if (t < 3) {
        float p = 0.f;
        for (int a = lo; a < lo2; a++) p += pos[a*3 + t];
        cpos[m*3 + t] = p * inv;
    }
}

// ---------------- pack fp32 [L][K][256] weight -> bf16 MFMA B-fragment layout --------
__global__ void k_pack(const float* __restrict__ src, unsigned short* __restrict__ dst,
                       int K, int total)
{
    int idx = blockIdx.x * 256 + threadIdx.x;
    if (idx >= total) return;
    int n = idx % 256;
    int k = (idx / 256) % K;
    int l = idx / (256 * K);
    int KT = K >> 5;
    int nt = n >> 4, kt = k >> 5, q = (k >> 3) & 3, j = k & 7;
    int lane = q*16 + (n & 15);
    dst[l*(16*KT*512) + ((nt*KT + kt)*64 + lane)*8 + j] = f2bf(src[idx]);
}

// ---------------- pack w1 [L][64][256] -> bf16 MFMA A-fragment layout of w1^T ----
// A[m=f1][k=ech]: dst[((l*16+mt)*2+kt)*64*8 + lane*8 + j] = w1[ech][f1]
// with f1 = mt*16 + (lane&15), ech = kt*32 + (lane>>4)*8 + j
__global__ void k_packA(const float* __restrict__ src, unsigned short* __restrict__ dst,
                        int total)
{
    int idx = blockIdx.x * 256 + threadIdx.x;
    if (idx >= total) return;
    int j = idx & 7, lane = (idx >> 3) & 63, kt = (idx >> 9) & 1;
    int mt = (idx >> 10) & 15, l = idx >> 14;
    int ech = kt*32 + (lane >> 4)*8 + j;
    int f1  = mt*16 + (lane & 15);
    dst[idx] = f2bf(src[(l*64 + ech)*256 + f1]);
}

// ---------------- fused edge MLP + aggregation ----------------
// one WG (512 thr = 8 waves) per destination cluster c of molecule b.
// GEMM1 FLIPPED: computes G^T = w1^T(256x64) @ phi^T(64x64) so the MFMA C-layout
// holds 4 consecutive fil1 per lane -> packed b64 G-stores (8 stores vs 32 u16
// scatters), feeding GEMM2's A-frag [edge][fil1] b128 reads directly.
__global__ __launch_bounds__(512, 6) void k_edge(
    const float* __restrict__ cpos, const unsigned short* __restrict__ x_bf,
    const unsigned short* __restrict__ w1p, const unsigned short* __restrict__ w2p,
    const float* __restrict__ b1, const float* __restrict__ b2,
    unsigned short* __restrict__ agg_bf)
{
    __shared__ unsigned short G_s[64 * 256];     // 32KB, [edge][fil1] swizzled
    __shared__ unsigned short phi_s[64 * 64];    // 8KB, [edge][ech] chunk-swizzled
    __shared__ float d_s[64];
    __shared__ float C_s[64];

    const int wg = blockIdx.x;            // global dest cluster id
    const int b  = wg >> 6, c = wg & 63;
    const int t  = threadIdx.x;
    const int w  = t >> 6, lane = t & 63; // w = wave 0..7
    const int quad = lane >> 4, l16 = lane & 15;

    if (t < 64) {
        float ax = cpos[(b*64 + t)*3 + 0] - cpos[(b*64 + c)*3 + 0];
        float ay = cpos[(b*64 + t)*3 + 1] - cpos[(b*64 + c)*3 + 1];
        float az = cpos[(b*64 + t)*3 + 2] - cpos[(b*64 + c)*3 + 2];
        float d = sqrtf(ax*ax + ay*ay + az*az);
        d_s[t] = d;
        float Cv = 0.5f * (__cosf(d * 0.31415926535897932f) + 1.0f); // pi/10
        Cv = (d <= 10.0f) ? Cv : 0.0f;
        if (t == c) Cv = 0.0f;            // no self edge
        C_s[t] = Cv;
    }
    __syncthreads();

    // ---- cooperative gaussian features phi[64 edges][64 ch]
    const float DELTA = 10.0f / 63.0f;
    const float C2 = (-0.5f / (DELTA * DELTA)) * 1.44269504088896341f; // coeff*log2(e)
    {
        float d = d_s[lane];
        u16x8 ph;
        #pragma unroll
        for (int j = 0; j < 8; j++) {
            float diff = d - (float)(w*8 + j) * DELTA;
            ph[j] = f2bf(__builtin_amdgcn_exp2f(C2 * diff * diff));
        }
        *reinterpret_cast<u16x8*>(&phi_s[lane*64 + ((w ^ phi_sw(lane)) << 3)]) = ph;
    }
    __syncthreads();

    // ---- GEMM1': G^T[f1, edge] = w1^T @ phi^T. Wave owns 2 f1 m-tiles, all 4 edge n-tiles.
    f32x4 acc1[2][4];
    #pragma unroll
    for (int a = 0; a < 2; a++)
        #pragma unroll
        for (int bb = 0; bb < 4; bb++) acc1[a][bb] = f32x4{0.f,0.f,0.f,0.f};

    #pragma unroll
    for (int kt = 0; kt < 2; kt++) {
        bf16x8 bfr[4];
        #pragma unroll
        for (int nt = 0; nt < 4; nt++) {
            int row = nt*16 + l16;
            bfr[nt] = *reinterpret_cast<const bf16x8*>(
                &phi_s[row*64 + (((kt*4 + quad) ^ phi_sw(row)) << 3)]);
        }
        #pragma unroll
        for (int mt = 0; mt < 2; mt++) {
            bf16x8 afr = *reinterpret_cast<const bf16x8*>(
                w1p + (((w*2 + mt)*2 + kt)*64 + lane)*8);
            #pragma unroll
            for (int nt = 0; nt < 4; nt++)
                acc1[mt][nt] = __builtin_amdgcn_mfma_f32_16x16x32_bf16(afr, bfr[nt], acc1[mt][nt], 0, 0, 0);
        }
    }

    // ---- bias + ssp + C-fold + packed b64 store to G_s[edge][fil1]
    float Cn[4];
    #pragma unroll
    for (int nt = 0; nt < 4; nt++) Cn[nt] = C_s[nt*16 + l16];

    #pragma unroll
    for (int mt = 0; mt < 2; mt++) {
        const int f1b = (w*2 + mt)*16 + quad*4;
        float4 bq = *reinterpret_cast<const float4*>(&b1[f1b]);
        float bb[4] = {bq.x, bq.y, bq.z, bq.w};
        #pragma unroll
        for (int nt = 0; nt < 4; nt++) {
            float v0 = ssp_fast(acc1[mt][nt][0] + bb[0]) * Cn[nt];
            float v1 = ssp_fast(acc1[mt][nt][1] + bb[1]) * Cn[nt];
            float v2 = ssp_fast(acc1[mt][nt][2] + bb[2]) * Cn[nt];
            float v3 = ssp_fast(acc1[mt][nt][3] + bb[3]) * Cn[nt];
            uint2 pp;
            pp.x = pk2(v0, v1);
            pp.y = pk2(v2, v3);
            int edge = nt*16 + l16;
            int s = (edge + (edge >> 3)) & 7;
            int a = edge*256 + ((((f1b >> 3) ^ s) << 3) | (f1b & 7));
            *reinterpret_cast<uint2*>(&G_s[a]) = pp;
        }
    }
    __syncthreads();

    // ---- GEMM2: G~(64x256) @ w2(256x256). A from LDS b128, wave owns 2 f2 nt-tiles.
    f32x4 acc2[4][2];
    #pragma unroll
    for (int a = 0; a < 4; a++)
        #pragma unroll
        for (int bb = 0; bb < 2; bb++) acc2[a][bb] = f32x4{0.f,0.f,0.f,0.f};

    #pragma unroll
    for (int kt = 0; kt < 8; kt++) {
        bf16x8 afr[4];
        #pragma unroll
        for (int mt = 0; mt < 4; mt++) {
            int row = mt*16 + l16;
            int s = (row + (row >> 3)) & 7;
            afr[mt] = *reinterpret_cast<const bf16x8*>(&G_s[row*256 + (((kt*4 + quad) ^ s) << 3)]);
        }
        #pragma unroll
        for (int nt = 0; nt < 2; nt++) {
            const int ntg = w*2 + nt;
            bf16x8 bfr = *reinterpret_cast<const bf16x8*>(w2p + ((ntg*8 + kt)*64 + lane)*8);
            #pragma unroll
            for (int mt = 0; mt < 4; mt++)
                acc2[mt][nt] = __builtin_amdgcn_mfma_f32_16x16x32_bf16(afr[mt], bfr, acc2[mt][nt], 0, 0, 0);
        }
    }

    // ---- epilogue: agg[c,f] = sum_r x[r,f]*acc2[r,f] + b2[f]*sum_r x[r,f]*C[r]
    float b2v[2];
    #pragma unroll
    for (int nt = 0; nt < 2; nt++) b2v[nt] = b2[(w*2 + nt)*16 + l16];

    const unsigned short* xb = x_bf + (size_t)b * 64 * 256;
    float colsum[2] = {0.f, 0.f};
    float xcsum[2]  = {0.f, 0.f};

    unsigned short xpre[2][8];
    #pragma unroll
    for (int e = 0; e < 8; e++) {
        int nt = e >> 2, i = e & 3;
        xpre[0][e] = xb[(quad*4 + i)*256 + (w*2 + nt)*16 + l16];
    }
    #pragma unroll
    for (int mt = 0; mt < 4; mt++) {
        if (mt < 3) {
            #pragma unroll
            for (int e = 0; e < 8; e++) {
                int nt = e >> 2, i = e & 3;
                xpre[(mt+1)&1][e] = xb[((mt+1)*16 + quad*4 + i)*256 + (w*2 + nt)*16 + l16];
            }
        }
        float Cr[4];
        #pragma unroll
        for (int i = 0; i < 4; i++) Cr[i] = C_s[mt*16 + quad*4 + i];
        #pragma unroll
        for (int nt = 0; nt < 2; nt++)
            #pragma unroll
            for (int i = 0; i < 4; i++) {
                float xv = bf2f(xpre[mt&1][nt*4 + i]);
                colsum[nt] = fmaf(xv, acc2[mt][nt][i], colsum[nt]);
                xcsum[nt] = fmaf(xv, Cr[i], xcsum[nt]);
            }
    }
    #pragma unroll
    for (int nt = 0; nt < 2; nt++) {
        colsum[nt] = fmaf(b2v[nt], xcsum[nt], colsum[nt]);
        colsum[nt] += __shfl_xor(colsum[nt], 16, 64);
        colsum[nt] += __shfl_xor(colsum[nt], 32, 64);
    }
    if (quad == 0) {
        #pragma unroll
        for (int nt = 0; nt < 2; nt++)
            agg_bf[(size_t)wg*256 + (w*2 + nt)*16 + l16] = f2bf(colsum[nt]);
    }
}

// ---------------- 16-row-tile GEMM helper over swizzled LDS A ----------------
__device__ __forceinline__ void gemm16(const unsigned short* A_s, const unsigned short* Bp,
                                       int w, int lane, f32x4 acc[4])
{
    const int quad = lane >> 4, l16 = lane & 15;
    const int s = (l16 + (l16 >> 3)) & 7;
    #pragma unroll
    for (int nt = 0; nt < 4; nt++) acc[nt] = f32x4{0.f,0.f,0.f,0.f};
    #pragma unroll
    for (int kt = 0; kt < 8; kt++) {
        bf16x8 afr = *reinterpret_cast<const bf16x8*>(&A_s[l16*256 + (((kt*4 + quad) ^ s) << 3)]);
        #pragma unroll
        for (int nt = 0; nt < 4; nt++) {
            bf16x8 bfr = *reinterpret_cast<const bf16x8*>(Bp + (((w*4 + nt)*8 + kt)*64 + lane)*8);
            acc[nt] = __builtin_amdgcn_mfma_f32_16x16x32_bf16(afr, bfr, acc[nt], 0, 0, 0);
        }
    }
}

// ---------------- initial x0 = h @ lin1 (4096x256)@(256x256) ----------------
__global__ __launch_bounds__(256) void k_gemm0(
    const unsigned short* __restrict__ A_bf, const unsigned short* __restrict__ Bp,
    unsigned short* __restrict__ out_bf)
{
    __shared__ unsigned short A_s[16 * 256];
    const int mb = blockIdx.x;     // 256 blocks of 16 rows
    const int t = threadIdx.x;
    const int w = t >> 6, lane = t & 63, quad = lane >> 4, l16 = lane & 15;

    {   // stage 16x256 tile, swizzled
        int r = t >> 4, seg = t & 15;
        int s = (r + (r >> 3)) & 7;
        const u16x8* src = reinterpret_cast<const u16x8*>(A_bf + (size_t)(mb*16 + r)*256 + seg*16);
        int c = seg*2;
        *reinterpret_cast<u16x8*>(&A_s[r*256 + (((c  ) ^ s) << 3)]) = src[0];
        *reinterpret_cast<u16x8*>(&A_s[r*256 + (((c+1) ^ s) << 3)]) = src[1];
    }
    __syncthreads();

    f32x4 acc[4];
    gemm16(A_s, Bp, w, lane, acc);

    #pragma unroll
    for (int nt = 0; nt < 4; nt++)
        #pragma unroll
        for (int i = 0; i < 4; i++) {
            int rg = mb*16 + quad*4 + i;
            int col = w*64 + nt*16 + l16;
            out_bf[(size_t)rg*256 + col] = f2bf(acc[nt][i]);
        }
}

// ---------------- fused tail: y=ssp(agg@lin2+b2); h+=y@lin_w+b; x=h@lin1_next ----
template<int DO_X>
__global__ __launch_bounds__(256) void k_tail(
    const unsigned short* __restrict__ agg_bf,
    const unsigned short* __restrict__ lin2p, const float* __restrict__ lin2_b,
    const unsigned short* __restrict__ linp,  const float* __restrict__ lin_b,
    const unsigned short* __restrict__ lin1p,
    float* __restrict__ h, unsigned short* __restrict__ x_bf)
{
    __shared__ unsigned short A_s[16 * 256];
    const int mb = blockIdx.x;     // 256 blocks of 16 rows
    const int t = threadIdx.x;
    const int w = t >> 6, lane = t & 63, quad = lane >> 4, l16 = lane & 15;

    {   // stage agg 16x256 tile, swizzled
        int r = t >> 4, seg = t & 15;
        int s = (r + (r >> 3)) & 7;
        const u16x8* src = reinterpret_cast<const u16x8*>(agg_bf + (size_t)(mb*16 + r)*256 + seg*16);
        int c = seg*2;
        *reinterpret_cast<u16x8*>(&A_s[r*256 + (((c  ) ^ s) << 3)]) = src[0];
        *reinterpret_cast<u16x8*>(&A_s[r*256 + (((c+1) ^ s) << 3)]) = src[1];
    }
    __syncthreads();

    f32x4 acc[4];
    // stage 1: y = ssp(agg @ lin2 + lin2_b)
    gemm16(A_s, lin2p, w, lane, acc);
    float bv[4];
    #pragma unroll
    for (int nt = 0; nt < 4; nt++) bv[nt] = lin2_b[w*64 + nt*16 + l16];
    __syncthreads();
    #pragma unroll
    for (int nt = 0; nt < 4; nt++)
        #pragma unroll
        for (int i = 0; i < 4; i++) {
            int row = quad*4 + i, col = w*64 + nt*16 + l16;
            A_s[sw_off(row, col)] = f2bf(ssp_fast(acc[nt][i] + bv[nt]));
        }
    __syncthreads();

    // stage 2: h' = h + y @ lin_w + lin_b   (fp32 residual)
    gemm16(A_s, linp, w, lane, acc);
    #pragma unroll
    for (int nt = 0; nt < 4; nt++) bv[nt] = lin_b[w*64 + nt*16 + l16];
    float hv[4][4];
    #pragma unroll
    for (int nt = 0; nt < 4; nt++)
        #pragma unroll
        for (int i = 0; i < 4; i++) {
            int rg = mb*16 + quad*4 + i;
            int col = w*64 + nt*16 + l16;
            float v = acc[nt][i] + bv[nt] + h[(size_t)rg*256 + col];
            h[(size_t)rg*256 + col] = v;
            hv[nt][i] = v;
        }
    if (DO_X) {
        __syncthreads();
        #pragma unroll
        for (int nt = 0; nt < 4; nt++)
            #pragma unroll
            for (int i = 0; i < 4; i++) {
                int row = quad*4 + i, col = w*64 + nt*16 + l16;
                A_s[sw_off(row, col)] = f2bf(hv[nt][i]);
            }
        __syncthreads();
        // stage 3: x_next = h' @ lin1_next
        gemm16(A_s, lin1p, w, lane, acc);
        #pragma unroll
        for (int nt = 0; nt < 4; nt++)
            #pragma unroll
            for (int i = 0; i < 4; i++) {
                int rg = mb*16 + quad*4 + i;
                int col = w*64 + nt*16 + l16;
                x_bf[(size_t)rg*256 + col] = f2bf(acc[nt][i]);
            }
    }
}

// ---------------- host ----------------
extern "C" void kernel_launch(void* const* d_in, const int* in_sizes, int n_in,
                              void* d_out, int out_size, void* d_ws, size_t ws_size,
                              hipStream_t stream)
{
    const float* pos    = (const float*)d_in[0];
    const float* nattr  = (const float*)d_in[1];
    const int*   subi   = (const int*)d_in[2];
    const float* mlp_w1 = (const float*)d_in[6];
    const float* mlp_b1 = (const float*)d_in[7];
    const float* mlp_w2 = (const float*)d_in[8];
    const float* mlp_b2 = (const float*)d_in[9];
    const float* lin1_w = (const float*)d_in[10];
    const float* lin2_w = (const float*)d_in[11];
    const float* lin2_b = (const float*)d_in[12];
    const float* lin_w  = (const float*)d_in[13];
    const float* lin_b  = (const float*)d_in[14];
    float* h = (float*)d_out;        // fp32 h lives in d_out across all layers

    char* p = (char*)d_ws;
    auto alloc = [&](size_t bytes) { char* r = p; p += (bytes + 255) & ~(size_t)255; return r; };
    unsigned short* h_bf   = (unsigned short*)alloc((size_t)MCL*256*2);
    unsigned short* x_bf   = (unsigned short*)alloc((size_t)MCL*256*2);
    unsigned short* agg_bf = (unsigned short*)alloc((size_t)MCL*256*2);
    float*          cpos   = (float*)alloc((size_t)MCL*3*4);
    unsigned short* w1p    = (unsigned short*)alloc((size_t)LINT*16384*2);
    unsigned short* w2p    = (unsigned short*)alloc((size_t)LINT*65536*2);
    unsigned short* lin1p  = (unsigned short*)alloc((size_t)LINT*65536*2);
    unsigned short* lin2p  = (unsigned short*)alloc((size_t)LINT*65536*2);
    unsigned short* linp   = (unsigned short*)alloc((size_t)LINT*65536*2);

    k_coarse<<<MCL, 64, 0, stream>>>(pos, nattr, subi, h, h_bf, cpos);
    k_packA<<<(LINT*16384 + 255)/256, 256, 0, stream>>>(mlp_w1, w1p, LINT*16384);
    k_pack<<<(LINT*65536 + 255)/256, 256, 0, stream>>>(mlp_w2, w2p, 256, LINT*65536);
    k_pack<<<(LINT*65536 + 255)/256, 256, 0, stream>>>(lin1_w, lin1p, 256, LINT*65536);
    k_pack<<<(LINT*65536 + 255)/256, 256, 0, stream>>>(lin2_w, lin2p, 256, LINT*65536);
    k_pack<<<(LINT*65536 + 255)/256, 256, 0, stream>>>(lin_w,  linp,  256, LINT*65536);

    // x0 = h @ lin1[0]
    k_gemm0<<<256, 256, 0, stream>>>(h_bf, lin1p, x_bf);

    for (int l = 0; l < LINT; l++) {
        k_edge<<<MCL, 512, 0, stream>>>(cpos, x_bf, w1p + (size_t)l*16384, w2p + (size_t)l*65536,
                                        mlp_b1 + l*256, mlp_b2 + l*256, agg_bf);
        if (l < LINT-1) {
            k_tail<1><<<256, 256, 0, stream>>>(agg_bf, lin2p + (size_t)l*65536, lin2_b + l*256,
                                               linp + (size_t)l*65536, lin_b + l*256,
                                               lin1p + (size_t)(l+1)*65536, h, x_bf);
        } else {
            k_tail<0><<<256, 256, 0, stream>>>(agg_bf, lin2p + (size_t)l*65536, lin2_b + l*256,
                                               linp + (size_t)l*65536, lin_b + l*256,
                                               lin1p, h, x_bf);
        }
    }
}

// Round 8
// 482.829 us; speedup vs baseline: 1.6962x; 1.1560x over previous
//
#include <hip/hip_runtime.h>
#include <cstdint>

#define NATOMS 16384
#define BGRAPH 64
#define KC     64
#define MCL    (BGRAPH*KC)   // 4096 clusters
#define HIDC   256
#define FILC   256
#define ECHC   64
#define LINT   6

typedef __bf16 bf16x8 __attribute__((ext_vector_type(8)));
typedef __bf16 bf16x2 __attribute__((ext_vector_type(2)));
typedef float  f32x4  __attribute__((ext_vector_type(4)));
typedef unsigned short u16x8 __attribute__((ext_vector_type(8)));

__device__ __forceinline__ float bf2f(unsigned short u) {
    unsigned int x = ((unsigned int)u) << 16;
    return __builtin_bit_cast(float, x);
}
__device__ __forceinline__ unsigned short f2bf(float f) {
    unsigned int u = __builtin_bit_cast(unsigned int, f);
    u += 0x7FFFu + ((u >> 16) & 1u);   // RNE
    return (unsigned short)(u >> 16);
}
// packed f32x2 -> bf16x2 (low = first arg). gfx950 has v_cvt_pk_bf16_f32.
__device__ __forceinline__ unsigned int pk2(float a, float b) {
#if __has_builtin(__builtin_amdgcn_cvt_pk_bf16_f32)
    bf16x2 v = __builtin_amdgcn_cvt_pk_bf16_f32(a, b);
    return __builtin_bit_cast(unsigned int, v);
#else
    return (unsigned int)f2bf(a) | ((unsigned int)f2bf(b) << 16);
#endif
}
// fast shifted-softplus: log(1+e^x) - ln2, via raw v_exp_f32/v_log_f32 (base-2)
__device__ __forceinline__ float ssp_fast(float x) {
    float m = fmaxf(x, 0.0f);
    float t = __builtin_amdgcn_exp2f(-fabsf(x) * 1.44269504088896341f);
    float l = __builtin_amdgcn_logf(1.0f + t);           // log2(1+t), t<=1
    return fmaf(0.69314718055994531f, l, m - 0.69314718055994531f);
}
// XOR swizzle for 256-col bf16 LDS tiles (16B-chunk granularity)
__device__ __forceinline__ int sw_off(int row, int col) {
    int s = (row + (row >> 3)) & 7;
    return row * 256 + ((((col >> 3) ^ s) << 3) | (col & 7));
}
// row-dependent chunk swizzle for the 64-col phi tile
__device__ __forceinline__ int phi_sw(int row) {
    return ((row & 7) ^ ((row >> 3) & 7)) & 7;
}

// ---------------- coarse grain: scatter-mean atoms -> clusters ----------------
__global__ void k_coarse(const float* __restrict__ pos, const float* __restrict__ attr,
                         const int* __restrict__ subi,
                         float* __restrict__ h, unsigned short* __restrict__ h_bf,
                         float* __restrict__ cpos)
{
    const int m = blockIdx.x;
    const int t = threadIdx.x;             // 0..63
    const bool is64 = (subi[8] == 1);      // dtype sniff (i//4 pattern)
    int lo = 0, hi = NATOMS;
    while (lo < hi) { int mid = (lo + hi) >> 1;
        int v = is64 ? subi[2*mid] : subi[mid];
        if (v < m) lo = mid + 1; else hi = mid; }
    int lo2 = lo, hi2 = NATOMS;
    while (lo2 < hi2) { int mid = (lo2 + hi2) >> 1;
        int v = is64 ? subi[2*mid] : subi[mid];
        if (v < m + 1) lo2 = mid + 1; else hi2 = mid; }
    const int cnt = lo2 - lo;
    const float inv = 1.0f / (float)(cnt > 0 ? cnt : 1);

    float4 s = {0.f, 0.f, 0.f, 0.f};
    for (int a = lo; a < lo2; a++) {
        const float4 v = *reinterpret_cast<const float4*>(&attr[a*HIDC + t*4]);
        s.x += v.x; s.y += v.y; s.z += v.z; s.w += v.w;
    }
    s.x *= inv; s.y *= inv; s.z *= inv; s.w *= inv;
    *reinterpret_cast<float4*>(&h[m*HIDC + t*4]) = s;
    const int o = m*HIDC + t*4;
    h_bf[o+0] = f2bf(s.x); h_bf[o+1] = f2bf(s.y);
    h_bf[o+2] = f2bf(s.z); h_bf[o+3] = f2bf(s.w);
    if (t < 3) {
        float p = 0.f;
        for (int a = lo; a < lo2; a++) p += pos[a*3 + t];
        cpos[m*3 + t] = p * inv;
    }
}

// ---------------- pack fp32 [L][K][256] weight -> bf16 MFMA B-fragment layout --------
__global__ void k_pack(const float* __restrict__ src, unsigned short* __restrict__ dst,
                       int K, int total)
{
    int idx = blockIdx.x * 256 + threadIdx.x;
    if (idx >= total) return;
    int n = idx % 256;
    int k = (idx / 256) % K;
    int l = idx / (256 * K);
    int KT = K >> 5;
    int nt = n >> 4, kt = k >> 5, q = (k >> 3) & 3, j = k & 7;
    int lane = q*16 + (n & 15);
    dst[l*(16*KT*512) + ((nt*KT + kt)*64 + lane)*8 + j] = f2bf(src[idx]);
}

// ---------------- pack w1 [L][64][256] -> bf16 MFMA A-fragment layout of w1^T ----
__global__ void k_packA(const float* __restrict__ src, unsigned short* __restrict__ dst,
                        int total)
{
    int idx = blockIdx.x * 256 + threadIdx.x;
    if (idx >= total) return;
    int j = idx & 7, lane = (idx >> 3) & 63, kt = (idx >> 9) & 1;
    int mt = (idx >> 10) & 15, l = idx >> 14;
    int ech = kt*32 + (lane >> 4)*8 + j;
    int f1  = mt*16 + (lane & 15);
    dst[idx] = f2bf(src[(l*64 + ech)*256 + f1]);
}

// ---------------- symmetric fused edge MLP + two-sided aggregation ----------------
// One WG (512 thr = 8 waves) per (molecule, dest-tile-pair i<=j); 36 pairs of
// 8-cluster tiles per molecule -> 56% of the edge work vs one-WG-per-dest
// (filter S[r,c,f] is symmetric: depends only on distance).
// Edge index e = r_local*8 + c_local (r in Di, c in Dj); the 64-edge GEMM
// pipeline (phi -> GEMM1' -> ssp/C-fold -> GEMM2) is unchanged.
// Epilogue contracts the S-block with x on BOTH sides and writes slot-partials
// part[slot][dest][f] (bf16): slot s for dest in tile t is written by
// WG(min(s,t),max(s,t)) -- exactly one writer, no atomics. Diagonal WGs write
// side-j only (their 64 edges already contain both orderings).
__global__ __launch_bounds__(512, 6) void k_edge(
    const float* __restrict__ cpos, const unsigned short* __restrict__ x_bf,
    const unsigned short* __restrict__ w1p, const unsigned short* __restrict__ w2p,
    const float* __restrict__ b1, const float* __restrict__ b2,
    unsigned short* __restrict__ part)     // [8][MCL][256] bf16
{
    __shared__ unsigned short G_s[64 * 256];     // 32KB, [edge][fil1] swizzled
    __shared__ unsigned short phi_s[64 * 64];    // 8KB, [edge][ech] chunk-swizzled
    __shared__ float C_s[64];

    const int wg = blockIdx.x;            // b*36 + pair
    const int b  = wg / 36;
    int p = wg - b*36;
    int ti = 0;
    while (p >= 8 - ti) { p -= 8 - ti; ++ti; }
    const int tj = ti + p;                // ti <= tj
    const bool diag = (ti == tj);

    const int t  = threadIdx.x;
    const int w  = t >> 6, lane = t & 63; // w = wave 0..7
    const int quad = lane >> 4, l16 = lane & 15;
    const int qh = quad >> 1, ql = quad & 1;

    __shared__ float d_s[64];
    if (t < 64) {
        int r = t >> 3, c = t & 7;
        int ri = b*64 + ti*8 + r;
        int cj = b*64 + tj*8 + c;
        float ax = cpos[ri*3 + 0] - cpos[cj*3 + 0];
        float ay = cpos[ri*3 + 1] - cpos[cj*3 + 1];
        float az = cpos[ri*3 + 2] - cpos[cj*3 + 2];
        float d = sqrtf(ax*ax + ay*ay + az*az);
        d_s[t] = d;
        float Cv = 0.5f * (__cosf(d * 0.31415926535897932f) + 1.0f); // pi/10
        Cv = (d <= 10.0f) ? Cv : 0.0f;
        if (ri == cj) Cv = 0.0f;          // no self edge
        C_s[t] = Cv;
    }
    __syncthreads();

    // ---- gaussian features phi[64 edges][64 ch]
    const float DELTA = 10.0f / 63.0f;
    const float C2 = (-0.5f / (DELTA * DELTA)) * 1.44269504088896341f; // coeff*log2(e)
    {
        float d = d_s[lane];
        u16x8 ph;
        #pragma unroll
        for (int j = 0; j < 8; j++) {
            float diff = d - (float)(w*8 + j) * DELTA;
            ph[j] = f2bf(__builtin_amdgcn_exp2f(C2 * diff * diff));
        }
        *reinterpret_cast<u16x8*>(&phi_s[lane*64 + ((w ^ phi_sw(lane)) << 3)]) = ph;
    }
    __syncthreads();

    // ---- GEMM1': G^T[f1, edge] = w1^T @ phi^T. Wave owns 2 f1 m-tiles, 4 edge n-tiles.
    f32x4 acc1[2][4];
    #pragma unroll
    for (int a = 0; a < 2; a++)
        #pragma unroll
        for (int bb = 0; bb < 4; bb++) acc1[a][bb] = f32x4{0.f,0.f,0.f,0.f};

    #pragma unroll
    for (int kt = 0; kt < 2; kt++) {
        bf16x8 bfr[4];
        #pragma unroll
        for (int nt = 0; nt < 4; nt++) {
            int row = nt*16 + l16;
            bfr[nt] = *reinterpret_cast<const bf16x8*>(
                &phi_s[row*64 + (((kt*4 + quad) ^ phi_sw(row)) << 3)]);
        }
        #pragma unroll
        for (int mt = 0; mt < 2; mt++) {
            bf16x8 afr = *reinterpret_cast<const bf16x8*>(
                w1p + (((w*2 + mt)*2 + kt)*64 + lane)*8);
            #pragma unroll
            for (int nt = 0; nt < 4; nt++)
                acc1[mt][nt] = __builtin_amdgcn_mfma_f32_16x16x32_bf16(afr, bfr[nt], acc1[mt][nt], 0, 0, 0);
        }
    }

    // ---- bias + ssp + C-fold + packed b64 store to G_s[edge][fil1]
    float Cn[4];
    #pragma unroll
    for (int nt = 0; nt < 4; nt++) Cn[nt] = C_s[nt*16 + l16];

    #pragma unroll
    for (int mt = 0; mt < 2; mt++) {
        const int f1b = (w*2 + mt)*16 + quad*4;
        float4 bq = *reinterpret_cast<const float4*>(&b1[f1b]);
        float bb[4] = {bq.x, bq.y, bq.z, bq.w};
        #pragma unroll
        for (int nt = 0; nt < 4; nt++) {
            float v0 = ssp_fast(acc1[mt][nt][0] + bb[0]) * Cn[nt];
            float v1 = ssp_fast(acc1[mt][nt][1] + bb[1]) * Cn[nt];
            float v2 = ssp_fast(acc1[mt][nt][2] + bb[2]) * Cn[nt];
            float v3 = ssp_fast(acc1[mt][nt][3] + bb[3]) * Cn[nt];
            uint2 pp;
            pp.x = pk2(v0, v1);
            pp.y = pk2(v2, v3);
            int edge = nt*16 + l16;
            int s = (edge + (edge >> 3)) & 7;
            int a = edge*256 + ((((f1b >> 3) ^ s) << 3) | (f1b & 7));
            *reinterpret_cast<uint2*>(&G_s[a]) = pp;
        }
    }
    __syncthreads();

    // ---- GEMM2: G~(64x256) @ w2(256x256). acc2[e,f] = C*(ssp@w2)
    f32x4 acc2[4][2];
    #pragma unroll
    for (int a = 0; a < 4; a++)
        #pragma unroll
        for (int bb = 0; bb < 2; bb++) acc2[a][bb] = f32x4{0.f,0.f,0.f,0.f};

    #pragma unroll
    for (int kt = 0; kt < 8; kt++) {
        bf16x8 afr[4];
        #pragma unroll
        for (int mt = 0; mt < 4; mt++) {
            int row = mt*16 + l16;
            int s = (row + (row >> 3)) & 7;
            afr[mt] = *reinterpret_cast<const bf16x8*>(&G_s[row*256 + (((kt*4 + quad) ^ s) << 3)]);
        }
        #pragma unroll
        for (int nt = 0; nt < 2; nt++) {
            const int ntg = w*2 + nt;
            bf16x8 bfr = *reinterpret_cast<const bf16x8*>(w2p + ((ntg*8 + kt)*64 + lane)*8);
            #pragma unroll
            for (int mt = 0; mt < 4; mt++)
                acc2[mt][nt] = __builtin_amdgcn_mfma_f32_16x16x32_bf16(afr[mt], bfr, acc2[mt][nt], 0, 0, 0);
        }
    }

    // ---- two-sided epilogue.
    // Value (e,f): e = mt*16 + quad*4 + i -> r_local = mt*2 + qh, c_local = ql*4 + i.
    // W'[e,f] = acc2 + C[e]*b2[f]   (full filter incl. b2, C folds self-edge to 0)
    // side j (dest c in Dj): sum over r  -> in-thread over mt, cross-thread xor 32 (qh)
    // side i (dest r in Di): sum over c  -> in-thread over i,  cross-thread xor 16 (ql)
    float Ce[4][4];
    #pragma unroll
    for (int mt = 0; mt < 4; mt++)
        #pragma unroll
        for (int i = 0; i < 4; i++) Ce[mt][i] = C_s[mt*16 + quad*4 + i];

    const int xrow_i = b*64 + ti*8;   // rows of x for side-j weighting (sources r)
    const int xrow_j = b*64 + tj*8;   // rows of x for side-i weighting (sources c)

    #pragma unroll
    for (int nt = 0; nt < 2; nt++) {
        const int f = (w*2 + nt)*16 + l16;
        const float b2v = b2[f];
        float xr[4], xc[4];
        #pragma unroll
        for (int mt = 0; mt < 4; mt++)
            xr[mt] = bf2f(x_bf[(size_t)(xrow_i + mt*2 + qh)*256 + f]);
        #pragma unroll
        for (int i = 0; i < 4; i++)
            xc[i] = bf2f(x_bf[(size_t)(xrow_j + ql*4 + i)*256 + f]);

        float sj[4] = {0.f, 0.f, 0.f, 0.f};   // per i  (c_local = ql*4+i)
        float si[4] = {0.f, 0.f, 0.f, 0.f};   // per mt (r_local = mt*2+qh)
        #pragma unroll
        for (int mt = 0; mt < 4; mt++)
            #pragma unroll
            for (int i = 0; i < 4; i++) {
                float wv = fmaf(Ce[mt][i], b2v, acc2[mt][nt][i]);
                sj[i]  = fmaf(xr[mt], wv, sj[i]);
                si[mt] = fmaf(xc[i],  wv, si[mt]);
            }
        // side j: combine qh halves (lane bit 5)
        #pragma unroll
        for (int i = 0; i < 4; i++) sj[i] += __shfl_xor(sj[i], 32, 64);
        // side i: combine ql halves (lane bit 4)
        #pragma unroll
        for (int mt = 0; mt < 4; mt++) si[mt] += __shfl_xor(si[mt], 16, 64);

        if (qh == 0) {   // quads 0,1 write side-j: dest c = ql*4+i in tile tj, slot ti
            #pragma unroll
            for (int i = 0; i < 4; i++) {
                int dest = b*64 + tj*8 + ql*4 + i;
                part[((size_t)ti*MCL + dest)*256 + f] = f2bf(sj[i]);
            }
        }
        if (!diag && ql == 0) {  // quads 0,2 write side-i: dest r = mt*2+qh in tile ti, slot tj
            #pragma unroll
            for (int mt = 0; mt < 4; mt++) {
                int dest = b*64 + ti*8 + mt*2 + qh;
                part[((size_t)tj*MCL + dest)*256 + f] = f2bf(si[mt]);
            }
        }
    }
}

// ---------------- 16-row-tile GEMM helper over swizzled LDS A ----------------
__device__ __forceinline__ void gemm16(const unsigned short* A_s, const unsigned short* Bp,
                                       int w, int lane, f32x4 acc[4])
{
    const int quad = lane >> 4, l16 = lane & 15;
    const int s = (l16 + (l16 >> 3)) & 7;
    #pragma unroll
    for (int nt = 0; nt < 4; nt++) acc[nt] = f32x4{0.f,0.f,0.f,0.f};
    #pragma unroll
    for (int kt = 0; kt < 8; kt++) {
        bf16x8 afr = *reinterpret_cast<const bf16x8*>(&A_s[l16*256 + (((kt*4 + quad) ^ s) << 3)]);
        #pragma unroll
        for (int nt = 0; nt < 4; nt++) {
            bf16x8 bfr = *reinterpret_cast<const bf16x8*>(Bp + (((w*4 + nt)*8 + kt)*64 + lane)*8);
            acc[nt] = __builtin_amdgcn_mfma_f32_16x16x32_bf16(afr, bfr, acc[nt], 0, 0, 0);
        }
    }
}

// ---------------- initial x0 = h @ lin1 (4096x256)@(256x256) ----------------
__global__ __launch_bounds__(256) void k_gemm0(
    const unsigned short* __restrict__ A_bf, const unsigned short* __restrict__ Bp,
    unsigned short* __restrict__ out_bf)
{
    __shared__ unsigned short A_s[16 * 256];
    const int mb = blockIdx.x;     // 256 blocks of 16 rows
    const int t = threadIdx.x;
    const int w = t >> 6, lane = t & 63, quad = lane >> 4, l16 = lane & 15;

    {   // stage 16x256 tile, swizzled
        int r = t >> 4, seg = t & 15;
        int s = (r + (r >> 3)) & 7;
        const u16x8* src = reinterpret_cast<const u16x8*>(A_bf + (size_t)(mb*16 + r)*256 + seg*16);
        int c = seg*2;
        *reinterpret_cast<u16x8*>(&A_s[r*256 + (((c  ) ^ s) << 3)]) = src[0];
        *reinterpret_cast<u16x8*>(&A_s[r*256 + (((c+1) ^ s) << 3)]) = src[1];
    }
    __syncthreads();

    f32x4 acc[4];
    gemm16(A_s, Bp, w, lane, acc);

    #pragma unroll
    for (int nt = 0; nt < 4; nt++)
        #pragma unroll
        for (int i = 0; i < 4; i++) {
            int rg = mb*16 + quad*4 + i;
            int col = w*64 + nt*16 + l16;
            out_bf[(size_t)rg*256 + col] = f2bf(acc[nt][i]);
        }
}

// ---------------- fused tail: agg = sum(part); y=ssp(agg@lin2+b2); h+=y@lin_w+b;
//                  x=h@lin1_next ----
template<int DO_X>
__global__ __launch_bounds__(256) void k_tail(
    const unsigned short* __restrict__ part,   // [8][MCL][256] bf16
    const unsigned short* __restrict__ lin2p, const float* __restrict__ lin2_b,
    const unsigned short* __restrict__ linp,  const float* __restrict__ lin_b,
    const unsigned short* __restrict__ lin1p,
    float* __restrict__ h, unsigned short* __restrict__ x_bf)
{
    __shared__ unsigned short A_s[16 * 256];
    const int mb = blockIdx.x;     // 256 blocks of 16 rows
    const int t = threadIdx.x;
    const int w = t >> 6, lane = t & 63, quad = lane >> 4, l16 = lane & 15;

    {   // stage agg = sum over 8 slot-partials, 16x256 tile, swizzled
        int r = t >> 4, seg = t & 15;
        int s2 = (r + (r >> 3)) & 7;
        const int dest = mb*16 + r;
        float a16[16];
        #pragma unroll
        for (int q = 0; q < 16; q++) a16[q] = 0.f;
        #pragma unroll
        for (int s = 0; s < 8; s++) {
            const u16x8* src = reinterpret_cast<const u16x8*>(
                part + ((size_t)s*MCL + dest)*256 + seg*16);
            u16x8 va = src[0], vb = src[1];
            #pragma unroll
            for (int q = 0; q < 8; q++) {
                a16[q]   += bf2f(va[q]);
                a16[8+q] += bf2f(vb[q]);
            }
        }
        uint2 p0, p1;
        p0.x = pk2(a16[0], a16[1]);  p0.y = pk2(a16[2], a16[3]);
        p1.x = pk2(a16[4], a16[5]);  p1.y = pk2(a16[6], a16[7]);
        uint2 p2, p3;
        p2.x = pk2(a16[8], a16[9]);  p2.y = pk2(a16[10], a16[11]);
        p3.x = pk2(a16[12], a16[13]); p3.y = pk2(a16[14], a16[15]);
        int c = seg*2;
        uint2* d0 = reinterpret_cast<uint2*>(&A_s[r*256 + (((c  ) ^ s2) << 3)]);
        uint2* d1 = reinterpret_cast<uint2*>(&A_s[r*256 + (((c+1) ^ s2) << 3)]);
        d0[0] = p0; d0[1] = p1;
        d1[0] = p2; d1[1] = p3;
    }
    __syncthreads();

    f32x4 acc[4];
    // stage 1: y = ssp(agg @ lin2 + lin2_b)
    gemm16(A_s, lin2p, w, lane, acc);
    float bv[4];
    #pragma unroll
    for (int nt = 0; nt < 4; nt++) bv[nt] = lin2_b[w*64 + nt*16 + l16];
    __syncthreads();
    #pragma unroll
    for (int nt = 0; nt < 4; nt++)
        #pragma unroll
        for (int i = 0; i < 4; i++) {
            int row = quad*4 + i, col = w*64 + nt*16 + l16;
            A_s[sw_off(row, col)] = f2bf(ssp_fast(acc[nt][i] + bv[nt]));
        }
    __syncthreads();

    // stage 2: h' = h + y @ lin_w + lin_b   (fp32 residual)
    gemm16(A_s, linp, w, lane, acc);
    #pragma unroll
    for (int nt = 0; nt < 4; nt++) bv[nt] = lin_b[w*64 + nt*16 + l16];
    float hv[4][4];
    #pragma unroll
    for (int nt = 0; nt < 4; nt++)
        #pragma unroll
        for (int i = 0; i < 4; i++) {
            int rg = mb*16 + quad*4 + i;
            int col = w*64 + nt*16 + l16;
            float v = acc[nt][i] + bv[nt] + h[(size_t)rg*256 + col];
            h[(size_t)rg*256 + col] = v;
            hv[nt][i] = v;
        }
    if (DO_X) {
        __syncthreads();
        #pragma unroll
        for (int nt = 0; nt < 4; nt++)
            #pragma unroll
            for (int i = 0; i < 4; i++) {
                int row = quad*4 + i, col = w*64 + nt*16 + l16;
                A_s[sw_off(row, col)] = f2bf(hv[nt][i]);
            }
        __syncthreads();
        // stage 3: x_next = h' @ lin1_next
        gemm16(A_s, lin1p, w, lane, acc);
        #pragma unroll
        for (int nt = 0; nt < 4; nt++)
            #pragma unroll
            for (int i = 0; i < 4; i++) {
                int rg = mb*16 + quad*4 + i;
                int col = w*64 + nt*16 + l16;
                x_bf[(size_t)rg*256 + col] = f2bf(acc[nt][i]);
            }
    }
}

// ---------------- host ----------------
extern "C" void kernel_launch(void* const* d_in, const int* in_sizes, int n_in,
                              void* d_out, int out_size, void* d_ws, size_t ws_size,
                              hipStream_t stream)
{
    const float* pos    = (const float*)d_in[0];
    const float* nattr  = (const float*)d_in[1];
    const int*   subi   = (const int*)d_in[2];
    const float* mlp_w1 = (const float*)d_in[6];
    const float* mlp_b1 = (const float*)d_in[7];
    const float* mlp_w2 = (const float*)d_in[8];
    const float* mlp_b2 = (const float*)d_in[9];
    const float* lin1_w = (const float*)d_in[10];
    const float* lin2_w = (const float*)d_in[11];
    const float* lin2_b = (const float*)d_in[12];
    const float* lin_w  = (const float*)d_in[13];
    const float* lin_b  = (const float*)d_in[14];
    float* h = (float*)d_out;        // fp32 h lives in d_out across all layers

    char* p = (char*)d_ws;
    auto alloc = [&](size_t bytes) { char* r = p; p += (bytes + 255) & ~(size_t)255; return r; };
    unsigned short* h_bf   = (unsigned short*)alloc((size_t)MCL*256*2);
    unsigned short* x_bf   = (unsigned short*)alloc((size_t)MCL*256*2);
    unsigned short* part   = (unsigned short*)alloc((size_t)8*MCL*256*2);  // 16.8MB
    float*          cpos   = (float*)alloc((size_t)MCL*3*4);
    unsigned short* w1p    = (unsigned short*)alloc((size_t)LINT*16384*2);
    unsigned short* w2p    = (unsigned short*)alloc((size_t)LINT*65536*2);
    unsigned short* lin1p  = (unsigned short*)alloc((size_t)LINT*65536*2);
    unsigned short* lin2p  = (unsigned short*)alloc((size_t)LINT*65536*2);
    unsigned short* linp   = (unsigned short*)alloc((size_t)LINT*65536*2);

    k_coarse<<<MCL, 64, 0, stream>>>(pos, nattr, subi, h, h_bf, cpos);
    k_packA<<<(LINT*16384 + 255)/256, 256, 0, stream>>>(mlp_w1, w1p, LINT*16384);
    k_pack<<<(LINT*65536 + 255)/256, 256, 0, stream>>>(mlp_w2, w2p, 256, LINT*65536);
    k_pack<<<(LINT*65536 + 255)/256, 256, 0, stream>>>(lin1_w, lin1p, 256, LINT*65536);
    k_pack<<<(LINT*65536 + 255)/256, 256, 0, stream>>>(lin2_w, lin2p, 256, LINT*65536);
    k_pack<<<(LINT*65536 + 255)/256, 256, 0, stream>>>(lin_w,  linp,  256, LINT*65536);

    // x0 = h @ lin1[0]
    k_gemm0<<<256, 256, 0, stream>>>(h_bf, lin1p, x_bf);

    for (int l = 0; l < LINT; l++) {
        k_edge<<<BGRAPH*36, 512, 0, stream>>>(cpos, x_bf,
                                              w1p + (size_t)l*16384, w2p + (size_t)l*65536,
                                              mlp_b1 + l*256, mlp_b2 + l*256, part);
        if (l < LINT-1) {
            k_tail<1><<<256, 256, 0, stream>>>(part, lin2p + (size_t)l*65536, lin2_b + l*256,
                                               linp + (size_t)l*65536, lin_b + l*256,
                                               lin1p + (size_t)(l+1)*65536, h, x_bf);
        } else {
            k_tail<0><<<256, 256, 0, stream>>>(part, lin2p + (size_t)l*65536, lin2_b + l*256,
                                               linp + (size_t)l*65536, lin_b + l*256,
                                               lin1p, h, x_bf);
        }
    }
}

// Round 9
// 433.394 us; speedup vs baseline: 1.8897x; 1.1141x over previous
//
#include <hip/hip_runtime.h>
#include <cstdint>

#define NATOMS 16384
#define BGRAPH 64
#define KC     64
#define MCL    (BGRAPH*KC)   // 4096 clusters
#define HIDC   256
#define FILC   256
#define ECHC   64
#define LINT   6

typedef __bf16 bf16x8 __attribute__((ext_vector_type(8)));
typedef __bf16 bf16x2 __attribute__((ext_vector_type(2)));
typedef float  f32x4  __attribute__((ext_vector_type(4)));
typedef unsigned short u16x8 __attribute__((ext_vector_type(8)));

__device__ __forceinline__ float bf2f(unsigned short u) {
    unsigned int x = ((unsigned int)u) << 16;
    return __builtin_bit_cast(float, x);
}
__device__ __forceinline__ unsigned short f2bf(float f) {
    unsigned int u = __builtin_bit_cast(unsigned int, f);
    u += 0x7FFFu + ((u >> 16) & 1u);   // RNE
    return (unsigned short)(u >> 16);
}
// packed f32x2 -> bf16x2 (low = first arg). gfx950 has v_cvt_pk_bf16_f32.
__device__ __forceinline__ unsigned int pk2(float a, float b) {
#if __has_builtin(__builtin_amdgcn_cvt_pk_bf16_f32)
    bf16x2 v = __builtin_amdgcn_cvt_pk_bf16_f32(a, b);
    return __builtin_bit_cast(unsigned int, v);
#else
    return (unsigned int)f2bf(a) | ((unsigned int)f2bf(b) << 16);
#endif
}
// fast shifted-softplus: log(1+e^x) - ln2, via raw v_exp_f32/v_log_f32 (base-2)
__device__ __forceinline__ float ssp_fast(float x) {
    float m = fmaxf(x, 0.0f);
    float t = __builtin_amdgcn_exp2f(-fabsf(x) * 1.44269504088896341f);
    float l = __builtin_amdgcn_logf(1.0f + t);           // log2(1+t), t<=1
    return fmaf(0.69314718055994531f, l, m - 0.69314718055994531f);
}
// XOR swizzle for 256-col bf16 LDS tiles (16B-chunk granularity)
__device__ __forceinline__ int sw_off(int row, int col) {
    int s = (row + (row >> 3)) & 7;
    return row * 256 + ((((col >> 3) ^ s) << 3) | (col & 7));
}
// row-dependent chunk swizzle for the 64-col phi tile
__device__ __forceinline__ int phi_sw(int row) {
    return ((row & 7) ^ ((row >> 3) & 7)) & 7;
}

// ---------------- coarse grain: scatter-mean atoms -> clusters ----------------
__global__ void k_coarse(const float* __restrict__ pos, const float* __restrict__ attr,
                         const int* __restrict__ subi,
                         float* __restrict__ h, unsigned short* __restrict__ h_bf,
                         float* __restrict__ cpos)
{
    const int m = blockIdx.x;
    const int t = threadIdx.x;             // 0..63
    const bool is64 = (subi[8] == 1);      // dtype sniff (i//4 pattern)
    int lo = 0, hi = NATOMS;
    while (lo < hi) { int mid = (lo + hi) >> 1;
        int v = is64 ? subi[2*mid] : subi[mid];
        if (v < m) lo = mid + 1; else hi = mid; }
    int lo2 = lo, hi2 = NATOMS;
    while (lo2 < hi2) { int mid = (lo2 + hi2) >> 1;
        int v = is64 ? subi[2*mid] : subi[mid];
        if (v < m + 1) lo2 = mid + 1; else hi2 = mid; }
    const int cnt = lo2 - lo;
    const float inv = 1.0f / (float)(cnt > 0 ? cnt : 1);

    float4 s = {0.f, 0.f, 0.f, 0.f};
    for (int a = lo; a < lo2; a++) {
        const float4 v = *reinterpret_cast<const float4*>(&attr[a*HIDC + t*4]);
        s.x += v.x; s.y += v.y; s.z += v.z; s.w += v.w;
    }
    s.x *= inv; s.y *= inv; s.z *= inv; s.w *= inv;
    *reinterpret_cast<float4*>(&h[m*HIDC + t*4]) = s;
    const int o = m*HIDC + t*4;
    h_bf[o+0] = f2bf(s.x); h_bf[o+1] = f2bf(s.y);
    h_bf[o+2] = f2bf(s.z); h_bf[o+3] = f2bf(s.w);
    if (t < 3) {
        float p = 0.f;
        for (int a = lo; a < lo2; a++) p += pos[a*3 + t];
        cpos[m*3 + t] = p * inv;
    }
}

// ---------------- pack fp32 [L][K][256] weight -> bf16 MFMA B-fragment layout --------
__global__ void k_pack(const float* __restrict__ src, unsigned short* __restrict__ dst,
                       int K, int total)
{
    int idx = blockIdx.x * 256 + threadIdx.x;
    if (idx >= total) return;
    int n = idx % 256;
    int k = (idx / 256) % K;
    int l = idx / (256 * K);
    int KT = K >> 5;
    int nt = n >> 4, kt = k >> 5, q = (k >> 3) & 3, j = k & 7;
    int lane = q*16 + (n & 15);
    dst[l*(16*KT*512) + ((nt*KT + kt)*64 + lane)*8 + j] = f2bf(src[idx]);
}

// ---------------- pack w1 [L][64][256] -> bf16 MFMA A-fragment layout of w1^T ----
__global__ void k_packA(const float* __restrict__ src, unsigned short* __restrict__ dst,
                        int total)
{
    int idx = blockIdx.x * 256 + threadIdx.x;
    if (idx >= total) return;
    int j = idx & 7, lane = (idx >> 3) & 63, kt = (idx >> 9) & 1;
    int mt = (idx >> 10) & 15, l = idx >> 14;
    int ech = kt*32 + (lane >> 4)*8 + j;
    int f1  = mt*16 + (lane & 15);
    dst[idx] = f2bf(src[(l*64 + ech)*256 + f1]);
}

// ---------------- symmetric fused edge MLP + two-sided aggregation ----------------
// One WG (512 thr = 8 waves) per (molecule, dest-tile-pair i<=j); 36 pairs/molecule.
// Output partials are staged in LDS (overlay on dead phi_s) and written to global
// as full coalesced 512B rows (R8 wrote scattered 32B u16 runs -> 61MB HBM write
// from write-allocate amplification; logical is ~18MB).
#define OSTR 264   // out_s row stride (u16): +8 pad so rows hit different banks
__global__ __launch_bounds__(512, 6) void k_edge(
    const float* __restrict__ cpos, const unsigned short* __restrict__ x_bf,
    const unsigned short* __restrict__ w1p, const unsigned short* __restrict__ w2p,
    const float* __restrict__ b1, const float* __restrict__ b2,
    unsigned short* __restrict__ part)     // [8][MCL][256] bf16
{
    __shared__ unsigned short G_s[64 * 256];     // 32KB, [edge][fil1] swizzled
    __shared__ unsigned short phi_s[16 * OSTR];  // 8.25KB: phi (64x64) then out_s (16xOSTR)
    __shared__ float C_s[64];
    __shared__ float d_s[64];

    const int wg = blockIdx.x;            // b*36 + pair
    const int b  = wg / 36;
    int p = wg - b*36;
    int ti = 0;
    while (p >= 8 - ti) { p -= 8 - ti; ++ti; }
    const int tj = ti + p;                // ti <= tj
    const bool diag = (ti == tj);

    const int t  = threadIdx.x;
    const int w  = t >> 6, lane = t & 63; // w = wave 0..7
    const int quad = lane >> 4, l16 = lane & 15;
    const int qh = quad >> 1, ql = quad & 1;

    if (t < 64) {
        int r = t >> 3, c = t & 7;
        int ri = b*64 + ti*8 + r;
        int cj = b*64 + tj*8 + c;
        float ax = cpos[ri*3 + 0] - cpos[cj*3 + 0];
        float ay = cpos[ri*3 + 1] - cpos[cj*3 + 1];
        float az = cpos[ri*3 + 2] - cpos[cj*3 + 2];
        float d = sqrtf(ax*ax + ay*ay + az*az);
        d_s[t] = d;
        float Cv = 0.5f * (__cosf(d * 0.31415926535897932f) + 1.0f); // pi/10
        Cv = (d <= 10.0f) ? Cv : 0.0f;
        if (ri == cj) Cv = 0.0f;          // no self edge
        C_s[t] = Cv;
    }
    __syncthreads();

    // ---- gaussian features phi[64 edges][64 ch]
    const float DELTA = 10.0f / 63.0f;
    const float C2 = (-0.5f / (DELTA * DELTA)) * 1.44269504088896341f; // coeff*log2(e)
    {
        float d = d_s[lane];
        u16x8 ph;
        #pragma unroll
        for (int j = 0; j < 8; j++) {
            float diff = d - (float)(w*8 + j) * DELTA;
            ph[j] = f2bf(__builtin_amdgcn_exp2f(C2 * diff * diff));
        }
        *reinterpret_cast<u16x8*>(&phi_s[lane*64 + ((w ^ phi_sw(lane)) << 3)]) = ph;
    }
    __syncthreads();

    // ---- GEMM1': G^T[f1, edge] = w1^T @ phi^T. Wave owns 2 f1 m-tiles, 4 edge n-tiles.
    f32x4 acc1[2][4];
    #pragma unroll
    for (int a = 0; a < 2; a++)
        #pragma unroll
        for (int bb = 0; bb < 4; bb++) acc1[a][bb] = f32x4{0.f,0.f,0.f,0.f};

    #pragma unroll
    for (int kt = 0; kt < 2; kt++) {
        bf16x8 bfr[4];
        #pragma unroll
        for (int nt = 0; nt < 4; nt++) {
            int row = nt*16 + l16;
            bfr[nt] = *reinterpret_cast<const bf16x8*>(
                &phi_s[row*64 + (((kt*4 + quad) ^ phi_sw(row)) << 3)]);
        }
        #pragma unroll
        for (int mt = 0; mt < 2; mt++) {
            bf16x8 afr = *reinterpret_cast<const bf16x8*>(
                w1p + (((w*2 + mt)*2 + kt)*64 + lane)*8);
            #pragma unroll
            for (int nt = 0; nt < 4; nt++)
                acc1[mt][nt] = __builtin_amdgcn_mfma_f32_16x16x32_bf16(afr, bfr[nt], acc1[mt][nt], 0, 0, 0);
        }
    }

    // ---- bias + ssp + C-fold + packed b64 store to G_s[edge][fil1]
    float Cn[4];
    #pragma unroll
    for (int nt = 0; nt < 4; nt++) Cn[nt] = C_s[nt*16 + l16];

    #pragma unroll
    for (int mt = 0; mt < 2; mt++) {
        const int f1b = (w*2 + mt)*16 + quad*4;
        float4 bq = *reinterpret_cast<const float4*>(&b1[f1b]);
        float bb[4] = {bq.x, bq.y, bq.z, bq.w};
        #pragma unroll
        for (int nt = 0; nt < 4; nt++) {
            float v0 = ssp_fast(acc1[mt][nt][0] + bb[0]) * Cn[nt];
            float v1 = ssp_fast(acc1[mt][nt][1] + bb[1]) * Cn[nt];
            float v2 = ssp_fast(acc1[mt][nt][2] + bb[2]) * Cn[nt];
            float v3 = ssp_fast(acc1[mt][nt][3] + bb[3]) * Cn[nt];
            uint2 pp;
            pp.x = pk2(v0, v1);
            pp.y = pk2(v2, v3);
            int edge = nt*16 + l16;
            int s = (edge + (edge >> 3)) & 7;
            int a = edge*256 + ((((f1b >> 3) ^ s) << 3) | (f1b & 7));
            *reinterpret_cast<uint2*>(&G_s[a]) = pp;
        }
    }
    __syncthreads();   // G_s complete; also: all phi reads done (out_s overlay safe)

    // ---- GEMM2: G~(64x256) @ w2(256x256). acc2[e,f] = C*(ssp@w2)
    f32x4 acc2[4][2];
    #pragma unroll
    for (int a = 0; a < 4; a++)
        #pragma unroll
        for (int bb = 0; bb < 2; bb++) acc2[a][bb] = f32x4{0.f,0.f,0.f,0.f};

    #pragma unroll
    for (int kt = 0; kt < 8; kt++) {
        bf16x8 afr[4];
        #pragma unroll
        for (int mt = 0; mt < 4; mt++) {
            int row = mt*16 + l16;
            int s = (row + (row >> 3)) & 7;
            afr[mt] = *reinterpret_cast<const bf16x8*>(&G_s[row*256 + (((kt*4 + quad) ^ s) << 3)]);
        }
        #pragma unroll
        for (int nt = 0; nt < 2; nt++) {
            const int ntg = w*2 + nt;
            bf16x8 bfr = *reinterpret_cast<const bf16x8*>(w2p + ((ntg*8 + kt)*64 + lane)*8);
            #pragma unroll
            for (int mt = 0; mt < 4; mt++)
                acc2[mt][nt] = __builtin_amdgcn_mfma_f32_16x16x32_bf16(afr[mt], bfr, acc2[mt][nt], 0, 0, 0);
        }
    }

    // ---- two-sided epilogue into LDS out_s (rows 0-7: tj dests, 8-15: ti dests)
    unsigned short* out_s = phi_s;
    float Ce[4][4];
    #pragma unroll
    for (int mt = 0; mt < 4; mt++)
        #pragma unroll
        for (int i = 0; i < 4; i++) Ce[mt][i] = C_s[mt*16 + quad*4 + i];

    const int xrow_i = b*64 + ti*8;   // sources r (side-j weighting)
    const int xrow_j = b*64 + tj*8;   // sources c (side-i weighting)

    #pragma unroll
    for (int nt = 0; nt < 2; nt++) {
        const int f = (w*2 + nt)*16 + l16;
        const float b2v = b2[f];
        float xr[4], xc[4];
        #pragma unroll
        for (int mt = 0; mt < 4; mt++)
            xr[mt] = bf2f(x_bf[(size_t)(xrow_i + mt*2 + qh)*256 + f]);
        #pragma unroll
        for (int i = 0; i < 4; i++)
            xc[i] = bf2f(x_bf[(size_t)(xrow_j + ql*4 + i)*256 + f]);

        float sj[4] = {0.f, 0.f, 0.f, 0.f};   // per i  (c_local = ql*4+i)
        float si[4] = {0.f, 0.f, 0.f, 0.f};   // per mt (r_local = mt*2+qh)
        #pragma unroll
        for (int mt = 0; mt < 4; mt++)
            #pragma unroll
            for (int i = 0; i < 4; i++) {
                float wv = fmaf(Ce[mt][i], b2v, acc2[mt][nt][i]);
                sj[i]  = fmaf(xr[mt], wv, sj[i]);
                si[mt] = fmaf(xc[i],  wv, si[mt]);
            }
        #pragma unroll
        for (int i = 0; i < 4; i++) sj[i] += __shfl_xor(sj[i], 32, 64);
        #pragma unroll
        for (int mt = 0; mt < 4; mt++) si[mt] += __shfl_xor(si[mt], 16, 64);

        if (qh == 0) {
            #pragma unroll
            for (int i = 0; i < 4; i++)
                out_s[(ql*4 + i)*OSTR + f] = f2bf(sj[i]);
        }
        if (!diag && ql == 0) {
            #pragma unroll
            for (int mt = 0; mt < 4; mt++)
                out_s[(8 + mt*2 + qh)*OSTR + f] = f2bf(si[mt]);
        }
    }
    __syncthreads();

    // ---- coalesced part write: one u16x8 per thread, full 512B rows
    {
        int row = t >> 5, ck = t & 31;
        if (row < 8 || !diag) {
            int slot, dest;
            if (row < 8) { slot = ti; dest = b*64 + tj*8 + row; }
            else         { slot = tj; dest = b*64 + ti*8 + (row - 8); }
            u16x8 v = *reinterpret_cast<const u16x8*>(&out_s[row*OSTR + ck*8]);
            *reinterpret_cast<u16x8*>(&part[((size_t)slot*MCL + dest)*256 + ck*8]) = v;
        }
    }
}

// ---------------- 16-row-tile GEMM helper (256-thr version, 4 nt-tiles/wave) ----
__device__ __forceinline__ void gemm16(const unsigned short* A_s, const unsigned short* Bp,
                                       int w, int lane, f32x4 acc[4])
{
    const int quad = lane >> 4, l16 = lane & 15;
    const int s = (l16 + (l16 >> 3)) & 7;
    #pragma unroll
    for (int nt = 0; nt < 4; nt++) acc[nt] = f32x4{0.f,0.f,0.f,0.f};
    #pragma unroll
    for (int kt = 0; kt < 8; kt++) {
        bf16x8 afr = *reinterpret_cast<const bf16x8*>(&A_s[l16*256 + (((kt*4 + quad) ^ s) << 3)]);
        #pragma unroll
        for (int nt = 0; nt < 4; nt++) {
            bf16x8 bfr = *reinterpret_cast<const bf16x8*>(Bp + (((w*4 + nt)*8 + kt)*64 + lane)*8);
            acc[nt] = __builtin_amdgcn_mfma_f32_16x16x32_bf16(afr, bfr, acc[nt], 0, 0, 0);
        }
    }
}

// ---------------- 16-row-tile GEMM helper (512-thr version, 2 nt-tiles/wave) ----
__device__ __forceinline__ void gemm16w8(const unsigned short* A_s, const unsigned short* Bp,
                                         int w, int lane, f32x4 acc[2])
{
    const int quad = lane >> 4, l16 = lane & 15;
    const int s = (l16 + (l16 >> 3)) & 7;
    #pragma unroll
    for (int nt = 0; nt < 2; nt++) acc[nt] = f32x4{0.f,0.f,0.f,0.f};
    #pragma unroll
    for (int kt = 0; kt < 8; kt++) {
        bf16x8 afr = *reinterpret_cast<const bf16x8*>(&A_s[l16*256 + (((kt*4 + quad) ^ s) << 3)]);
        #pragma unroll
        for (int nt = 0; nt < 2; nt++) {
            bf16x8 bfr = *reinterpret_cast<const bf16x8*>(Bp + (((w*2 + nt)*8 + kt)*64 + lane)*8);
            acc[nt] = __builtin_amdgcn_mfma_f32_16x16x32_bf16(afr, bfr, acc[nt], 0, 0, 0);
        }
    }
}

// ---------------- initial x0 = h @ lin1 (4096x256)@(256x256) ----------------
__global__ __launch_bounds__(256) void k_gemm0(
    const unsigned short* __restrict__ A_bf, const unsigned short* __restrict__ Bp,
    unsigned short* __restrict__ out_bf)
{
    __shared__ unsigned short A_s[16 * 256];
    const int mb = blockIdx.x;     // 256 blocks of 16 rows
    const int t = threadIdx.x;
    const int w = t >> 6, lane = t & 63, quad = lane >> 4, l16 = lane & 15;

    {   // stage 16x256 tile, swizzled
        int r = t >> 4, seg = t & 15;
        int s = (r + (r >> 3)) & 7;
        const u16x8* src = reinterpret_cast<const u16x8*>(A_bf + (size_t)(mb*16 + r)*256 + seg*16);
        int c = seg*2;
        *reinterpret_cast<u16x8*>(&A_s[r*256 + (((c  ) ^ s) << 3)]) = src[0];
        *reinterpret_cast<u16x8*>(&A_s[r*256 + (((c+1) ^ s) << 3)]) = src[1];
    }
    __syncthreads();

    f32x4 acc[4];
    gemm16(A_s, Bp, w, lane, acc);

    #pragma unroll
    for (int nt = 0; nt < 4; nt++)
        #pragma unroll
        for (int i = 0; i < 4; i++) {
            int rg = mb*16 + quad*4 + i;
            int col = w*64 + nt*16 + l16;
            out_bf[(size_t)rg*256 + col] = f2bf(acc[nt][i]);
        }
}

// ---------------- fused tail (512 thr, 8 waves, 16 rows): agg=sum(part);
//                  y=ssp(agg@lin2+b2); h+=y@lin_w+b; x=h@lin1_next ----
template<int DO_X>
__global__ __launch_bounds__(512) void k_tail(
    const unsigned short* __restrict__ part,   // [8][MCL][256] bf16
    const unsigned short* __restrict__ lin2p, const float* __restrict__ lin2_b,
    const unsigned short* __restrict__ linp,  const float* __restrict__ lin_b,
    const unsigned short* __restrict__ lin1p,
    float* __restrict__ h, unsigned short* __restrict__ x_bf)
{
    __shared__ unsigned short A_s[16 * 256];
    const int mb = blockIdx.x;     // 256 blocks of 16 rows
    const int t = threadIdx.x;
    const int w = t >> 6, lane = t & 63, quad = lane >> 4, l16 = lane & 15;

    {   // stage agg = sum over 8 slot-partials; one u16x8 per thread
        int r = t >> 5, seg8 = t & 31;       // row 0..15, 8-col chunk 0..31
        int s2 = (r + (r >> 3)) & 7;
        const int dest = mb*16 + r;
        float a8[8];
        #pragma unroll
        for (int q = 0; q < 8; q++) a8[q] = 0.f;
        #pragma unroll
        for (int s = 0; s < 8; s++) {
            u16x8 v = *reinterpret_cast<const u16x8*>(
                part + ((size_t)s*MCL + dest)*256 + seg8*8);
            #pragma unroll
            for (int q = 0; q < 8; q++) a8[q] += bf2f(v[q]);
        }
        uint2 p0, p1;
        p0.x = pk2(a8[0], a8[1]);  p0.y = pk2(a8[2], a8[3]);
        p1.x = pk2(a8[4], a8[5]);  p1.y = pk2(a8[6], a8[7]);
        uint2* d = reinterpret_cast<uint2*>(&A_s[r*256 + ((seg8 ^ s2) << 3)]);
        d[0] = p0; d[1] = p1;
    }
    __syncthreads();

    f32x4 acc[2];
    // stage 1: y = ssp(agg @ lin2 + lin2_b)
    gemm16w8(A_s, lin2p, w, lane, acc);
    float bv[2];
    #pragma unroll
    for (int nt = 0; nt < 2; nt++) bv[nt] = lin2_b[(w*2 + nt)*16 + l16];
    __syncthreads();
    #pragma unroll
    for (int nt = 0; nt < 2; nt++)
        #pragma unroll
        for (int i = 0; i < 4; i++) {
            int row = quad*4 + i, col = (w*2 + nt)*16 + l16;
            A_s[sw_off(row, col)] = f2bf(ssp_fast(acc[nt][i] + bv[nt]));
        }
    __syncthreads();

    // stage 2: h' = h + y @ lin_w + lin_b   (fp32 residual)
    gemm16w8(A_s, linp, w, lane, acc);
    #pragma unroll
    for (int nt = 0; nt < 2; nt++) bv[nt] = lin_b[(w*2 + nt)*16 + l16];
    float hv[2][4];
    #pragma unroll
    for (int nt = 0; nt < 2; nt++)
        #pragma unroll
        for (int i = 0; i < 4; i++) {
            int rg = mb*16 + quad*4 + i;
            int col = (w*2 + nt)*16 + l16;
            float v = acc[nt][i] + bv[nt] + h[(size_t)rg*256 + col];
            h[(size_t)rg*256 + col] = v;
            hv[nt][i] = v;
        }
    if (DO_X) {
        __syncthreads();
        #pragma unroll
        for (int nt = 0; nt < 2; nt++)
            #pragma unroll
            for (int i = 0; i < 4; i++) {
                int row = quad*4 + i, col = (w*2 + nt)*16 + l16;
                A_s[sw_off(row, col)] = f2bf(hv[nt][i]);
            }
        __syncthreads();
        // stage 3: x_next = h' @ lin1_next
        gemm16w8(A_s, lin1p, w, lane, acc);
        #pragma unroll
        for (int nt = 0; nt < 2; nt++)
            #pragma unroll
            for (int i = 0; i < 4; i++) {
                int rg = mb*16 + quad*4 + i;
                int col = (w*2 + nt)*16 + l16;
                x_bf[(size_t)rg*256 + col] = f2bf(acc[nt][i]);
            }
    }
}

// ---------------- host ----------------
extern "C" void kernel_launch(void* const* d_in, const int* in_sizes, int n_in,
                              void* d_out, int out_size, void* d_ws, size_t ws_size,
                              hipStream_t stream)
{
    const float* pos    = (const float*)d_in[0];
    const float* nattr  = (const float*)d_in[1];
    const int*   subi   = (const int*)d_in[2];
    const float* mlp_w1 = (const float*)d_in[6];
    const float* mlp_b1 = (const float*)d_in[7];
    const float* mlp_w2 = (const float*)d_in[8];
    const float* mlp_b2 = (const float*)d_in[9];
    const float* lin1_w = (const float*)d_in[10];
    const float* lin2_w = (const float*)d_in[11];
    const float* lin2_b = (const float*)d_in[12];
    const float* lin_w  = (const float*)d_in[13];
    const float* lin_b  = (const float*)d_in[14];
    float* h = (float*)d_out;        // fp32 h lives in d_out across all layers

    char* p = (char*)d_ws;
    auto alloc = [&](size_t bytes) { char* r = p; p += (bytes + 255) & ~(size_t)255; return r; };
    unsigned short* h_bf   = (unsigned short*)alloc((size_t)MCL*256*2);
    unsigned short* x_bf   = (unsigned short*)alloc((size_t)MCL*256*2);
    unsigned short* part   = (unsigned short*)alloc((size_t)8*MCL*256*2);  // 16.8MB
    float*          cpos   = (float*)alloc((size_t)MCL*3*4);
    unsigned short* w1p    = (unsigned short*)alloc((size_t)LINT*16384*2);
    unsigned short* w2p    = (unsigned short*)alloc((size_t)LINT*65536*2);
    unsigned short* lin1p  = (unsigned short*)alloc((size_t)LINT*65536*2);
    unsigned short* lin2p  = (unsigned short*)alloc((size_t)LINT*65536*2);
    unsigned short* linp   = (unsigned short*)alloc((size_t)LINT*65536*2);

    k_coarse<<<MCL, 64, 0, stream>>>(pos, nattr, subi, h, h_bf, cpos);
    k_packA<<<(LINT*16384 + 255)/256, 256, 0, stream>>>(mlp_w1, w1p, LINT*16384);
    k_pack<<<(LINT*65536 + 255)/256, 256, 0, stream>>>(mlp_w2, w2p, 256, LINT*65536);
    k_pack<<<(LINT*65536 + 255)/256, 256, 0, stream>>>(lin1_w, lin1p, 256, LINT*65536);
    k_pack<<<(LINT*65536 + 255)/256, 256, 0, stream>>>(lin2_w, lin2p, 256, LINT*65536);
    k_pack<<<(LINT*65536 + 255)/256, 256, 0, stream>>>(lin_w,  linp,  256, LINT*65536);

    // x0 = h @ lin1[0]
    k_gemm0<<<256, 256, 0, stream>>>(h_bf, lin1p, x_bf);

    for (int l = 0; l < LINT; l++) {
        k_edge<<<BGRAPH*36, 512, 0, stream>>>(cpos, x_bf,
                                              w1p + (size_t)l*16384, w2p + (size_t)l*65536,
                                              mlp_b1 + l*256, mlp_b2 + l*256, part);
        if (l < LINT-1) {
            k_tail<1><<<256, 512, 0, stream>>>(part, lin2p + (size_t)l*65536, lin2_b + l*256,
                                               linp + (size_t)l*65536, lin_b + l*256,
                                               lin1p + (size_t)(l+1)*65536, h, x_bf);
        } else {
            k_tail<0><<<256, 512, 0, stream>>>(part, lin2p + (size_t)l*65536, lin2_b + l*256,
                                               linp + (size_t)l*65536, lin_b + l*256,
                                               lin1p, h, x_bf);
        }
    }
}